// Round 18
// baseline (847.518 us; speedup 1.0000x reference)
//
#include <hip/hip_runtime.h>
#include <hip/hip_bf16.h>
#include <math.h>

#define SGRID 9216      // 96*96
#define NANCH 82944     // 9216*9
#define NSORT 131072    // pow2 >= worst-case candidate count (82944)
#define TOPM  8192      // phase-A window (sorted prefix)
#define MAXOUT 2000
#define OCB 16
#define XPS 104         // xpad row stride (float4-aligned)
#define XCS (98 * XPS)  // xpad channel stride = 10192

// ---------- helpers ----------
__device__ __forceinline__ bool iou_gt07(const float4 bi, const float4 bj) {
  float a1 = __fmul_rn(bi.z - bi.x, bi.w - bi.y);
  float a2 = __fmul_rn(bj.z - bj.x, bj.w - bj.y);
  float xx1 = fmaxf(bi.x, bj.x), yy1 = fmaxf(bi.y, bj.y);
  float xx2 = fminf(bi.z, bj.z), yy2 = fminf(bi.w, bj.w);
  float inter = __fmul_rn(fmaxf(xx2 - xx1, 0.f), fmaxf(yy2 - yy1, 0.f));
  float den = ((a1 + a2) - inter) + 1e-9f;
  return __fdiv_rn(inter, den) > 0.7f;
}

// ---------- init ----------
__global__ void k_init(unsigned long long* keys, unsigned int* ctrs) {
  int i = blockIdx.x * 256 + threadIdx.x;
  if (i < NSORT) keys[i] = 0ull;
  if (i < 8) ctrs[i] = 0u;
}

// ---------- pad x into [256][98][104] (zero border, stride 104) ----------
__global__ void k_pad(const float* __restrict__ x, float* __restrict__ xpad) {
  for (size_t i = (size_t)blockIdx.x * 256 + threadIdx.x; i < (size_t)256 * XCS;
       i += (size_t)gridDim.x * 256) {
    int ic = (int)(i / XCS);
    int rem = (int)(i % XCS);
    int yy = rem / XPS, xx = rem % XPS;
    float v = 0.f;
    if (yy >= 1 && yy <= 96 && xx >= 1 && xx <= 96)
      v = x[(size_t)ic * SGRID + (yy - 1) * 96 + (xx - 1)];
    xpad[i] = v;
  }
}

// ---------- reorder weights into [32 chunk][256 oc][72] ----------
__global__ void k_wre(const float* __restrict__ w, float* __restrict__ wre) {
  for (size_t i = (size_t)blockIdx.x * 256 + threadIdx.x; i < (size_t)32 * 256 * 72;
       i += (size_t)gridDim.x * 256) {
    int c = (int)(i / (256 * 72));
    int rem = (int)(i % (256 * 72));
    int oc = rem / 72, j = rem % 72;
    wre[i] = w[(size_t)oc * 2304 + c * 72 + j];
  }
}

// ---------- conv 3x3 (256->256, SAME, relu): reg-dbuf, 1 barrier/chunk ----------
// grid (96 rows, 16 oc-groups of 16), block 128 = 8 og (2 oc each) x 16 xg (6 x each)
// x reads via float2 (ds_read_b64, conflict-free); FMA chain identical to r11/r17
__global__ __launch_bounds__(128) void k_conv3(const float* __restrict__ xpad,
                                               const float* __restrict__ wre,
                                               const float* __restrict__ bias,
                                               float* __restrict__ h) {
  __shared__ float xsB[2][8][320];   // 8 ic x (3 rows x 104)
  __shared__ float wB[2][1152];      // 16 oc x 72
  const int y = blockIdx.x;
  const int oc0 = blockIdx.y * OCB;
  const int t = threadIdx.x;
  const int og = t >> 4;             // 8 groups of 2 oc
  const int xg = t & 15;             // 16 groups of 6 x
  float acc[2][6];
#pragma unroll
  for (int a = 0; a < 2; a++)
#pragma unroll
    for (int c = 0; c < 6; c++) acc[a][c] = 0.f;

  // staging assignments (chunk-independent): x = 624 float4, w = 288 float4
  int xg_ofs[5], xl_ofs[5];
  bool xon[5];
#pragma unroll
  for (int k = 0; k < 5; k++) {
    int idx = t + k * 128;
    xon[k] = (idx < 624);
    int rowidx = idx / 26, col = idx - rowidx * 26;
    int ic = rowidx / 3, r = rowidx - ic * 3;
    if (!xon[k]) { ic = 0; r = 0; col = 0; }
    xg_ofs[k] = ic * XCS + (y + r) * XPS + col * 4;
    xl_ofs[k] = ic * 320 + r * XPS + col * 4;
  }
  bool won[3];
#pragma unroll
  for (int k = 0; k < 3; k++) won[k] = ((t + k * 128) < 288);

  float4 xv[5], wv[3];
  auto ldreg = [&](int c) {
    const float* xb = xpad + (size_t)c * 8 * XCS;
    const float* wb = wre + ((size_t)c * 256 + oc0) * 72;
#pragma unroll
    for (int k = 0; k < 5; k++)
      if (xon[k]) xv[k] = *(const float4*)(xb + xg_ofs[k]);
#pragma unroll
    for (int k = 0; k < 3; k++)
      if (won[k]) wv[k] = *(const float4*)(wb + (t + k * 128) * 4);
  };
  auto stlds = [&](int buf) {
    float* xd = &xsB[buf][0][0];
#pragma unroll
    for (int k = 0; k < 5; k++)
      if (xon[k]) *(float4*)(xd + xl_ofs[k]) = xv[k];
#pragma unroll
    for (int k = 0; k < 3; k++)
      if (won[k]) *(float4*)(&wB[buf][(t + k * 128) * 4]) = wv[k];
  };

  ldreg(0);
  stlds(0);
  ldreg(1);
  __syncthreads();
  int buf = 0;
  for (int c = 0; c < 32; c++) {
    if (c < 31) {
      stlds(buf ^ 1);
      if (c < 30) ldreg(c + 2);
    }
#pragma unroll
    for (int ic = 0; ic < 8; ic++) {
#pragma unroll
      for (int r = 0; r < 3; r++) {
        // 8-col window via 4x float2 (8B-aligned: all offsets even)
        const float* xrow = &xsB[buf][ic][r * XPS + xg * 6];
        float2 p0 = *(const float2*)(xrow);
        float2 p1 = *(const float2*)(xrow + 2);
        float2 p2 = *(const float2*)(xrow + 4);
        float2 p3 = *(const float2*)(xrow + 6);
        float xr[8] = {p0.x, p0.y, p1.x, p1.y, p2.x, p2.y, p3.x, p3.y};
#pragma unroll
        for (int a = 0; a < 2; a++) {
          float w0 = wB[buf][(og * 2 + a) * 72 + ic * 9 + r * 3 + 0];
          float w1 = wB[buf][(og * 2 + a) * 72 + ic * 9 + r * 3 + 1];
          float w2 = wB[buf][(og * 2 + a) * 72 + ic * 9 + r * 3 + 2];
#pragma unroll
          for (int c2 = 0; c2 < 6; c2++)
            acc[a][c2] += xr[c2] * w0 + xr[c2 + 1] * w1 + xr[c2 + 2] * w2;
        }
      }
    }
    __syncthreads();
    buf ^= 1;
  }
#pragma unroll
  for (int a = 0; a < 2; a++) {
    int oc = oc0 + og * 2 + a;
    float bb = bias[oc];
#pragma unroll
    for (int c = 0; c < 6; c++) {
      float v = acc[a][c] + bb;
      h[(size_t)oc * SGRID + y * 96 + xg * 6 + c] = v > 0.f ? v : 0.f;
    }
  }
}

// ---------- 1x1 heads: channel-split, grid (36 pos-groups, 3 ch-groups of 18) ----------
__global__ __launch_bounds__(256) void k_conv1x1(const float* __restrict__ h,
                                                 const float* __restrict__ bw, const float* __restrict__ bb,
                                                 const float* __restrict__ sw, const float* __restrict__ sb,
                                                 float* __restrict__ bbox, float* __restrict__ score) {
  __shared__ float wcat[18][256];
  const int t = threadIdx.x;
  const int cg = blockIdx.y;
  for (int idx = t; idx < 18 * 64; idx += 256) {
    int cl = idx >> 6, k4 = idx & 63;
    int c = cg * 18 + cl;
    const float* src = (c < 36) ? (bw + c * 256) : (sw + (c - 36) * 256);
    float4 v = *(const float4*)(src + k4 * 4);
    *(float4*)(&wcat[cl][k4 * 4]) = v;
  }
  __syncthreads();
  const int p = blockIdx.x * 256 + t;
  float accA[18];
#pragma unroll
  for (int cl = 0; cl < 18; cl++) accA[cl] = 0.f;
  for (int k0 = 0; k0 < 256; k0 += 8) {
    float ha[8];
#pragma unroll
    for (int u = 0; u < 8; u++) ha[u] = h[(size_t)(k0 + u) * SGRID + p];
#pragma unroll
    for (int cl = 0; cl < 18; cl++) {
      float4 w0 = *(const float4*)(&wcat[cl][k0]);
      float4 w1 = *(const float4*)(&wcat[cl][k0 + 4]);
      accA[cl] += ha[0] * w0.x + ha[1] * w0.y + ha[2] * w0.z + ha[3] * w0.w
                + ha[4] * w1.x + ha[5] * w1.y + ha[6] * w1.z + ha[7] * w1.w;
    }
  }
#pragma unroll
  for (int cl = 0; cl < 18; cl++) {
    int c = cg * 18 + cl;
    if (c < 36) {
      float va = accA[cl] + bb[c];
      bbox[(size_t)c * SGRID + p] = va > 0.f ? va : 0.f;
    } else {
      float va = accA[cl] + sb[c - 36];
      score[(size_t)(c - 36) * SGRID + p] = va > 0.f ? va : 0.f;
    }
  }
}

// ---------- decode + filter + candidate compaction ----------
__global__ void k_decode(const float* __restrict__ bbox, const float* __restrict__ score,
                         float4* __restrict__ boxes, unsigned long long* __restrict__ keys,
                         unsigned int* __restrict__ cnt) {
  int a = blockIdx.x * 256 + threadIdx.x;
  if (a >= NANCH) return;
  int i = a / 864;
  int rem = a - i * 864;
  int j = rem / 9;
  int k = rem - j * 9;
  const double areas[3] = {16384.0, 65536.0, 262144.0};
  int ai = k / 3, ri = k - ai * 3;
  double wr = (ri == 1) ? 2.0 : 1.0;
  double hr = (ri == 2) ? 2.0 : 1.0;
  double u = sqrt(areas[ai] / (wr * hr));
  double wd = wr * u, hd = hr * u;
  double cxd = (i + 0.5) * 16.0, cyd = (j + 0.5) * 16.0;
  float ax1 = (float)(cxd - wd * 0.5), ax2 = (float)(cxd + wd * 0.5);
  float ay1 = (float)(cyd - hd * 0.5), ay2 = (float)(cyd + hd * 0.5);
  float wa = ax2 - ax1, haa = ay2 - ay1;
  float cxa = (ax1 + ax2) * 0.5f, cya = (ay1 + ay2) * 0.5f;

  float4 br = ((const float4*)bbox)[a];
  float o0 = score[2 * (size_t)a];

  float cx = __fmul_rn(br.x, wa) + cxa;
  float cy = __fmul_rn(br.y, haa) + cya;
  float ww = __fmul_rn(expf(br.z), wa);
  float hh = __fmul_rn(expf(br.w), haa);
  float x1 = fminf(fmaxf(cx - __fmul_rn(ww, 0.5f), 0.f), 1536.f);
  float y1 = fminf(fmaxf(cy - __fmul_rn(hh, 0.5f), 0.f), 1536.f);
  float x2 = fminf(fmaxf(cx + __fmul_rn(ww, 0.5f), 0.f), 1536.f);
  float y2 = fminf(fmaxf(cy + __fmul_rn(hh, 0.5f), 0.f), 1536.f);
  boxes[a] = make_float4(x1, y1, x2, y2);
  float area = fabsf(__fmul_rn(x1 - x2, y1 - y2));
  if (o0 > 0.2f && area > 100.0f) {
    unsigned p = atomicAdd(cnt, 1u);
    keys[p] = ((unsigned long long)__float_as_uint(o0) << 32) |
              (unsigned long long)(0xFFFFFFFFu - (unsigned)a);
  }
}

// ---------- bitonic sort (descending), cnt-aware stage skipping ----------
__global__ __launch_bounds__(1024) void k_sort_local(unsigned long long* keys,
                                                     const unsigned int* __restrict__ cntp) {
  __shared__ unsigned long long s[4096];
  const int base = blockIdx.x * 4096, t = threadIdx.x;
  if ((unsigned)base >= *cntp) return;
  for (int u = t; u < 4096; u += 1024) s[u] = keys[base + u];
  __syncthreads();
  for (int k = 2; k <= 4096; k <<= 1) {
    for (int j = k >> 1; j >= 1; j >>= 1) {
      for (int m = t; m < 2048; m += 1024) {
        int i = ((m & ~(j - 1)) << 1) | (m & (j - 1));
        int l = i | j;
        bool dir = (((base + i) & k) == 0);
        unsigned long long A = s[i], B = s[l];
        bool sw = dir ? (A < B) : (A > B);
        if (sw) { s[i] = B; s[l] = A; }
      }
      __syncthreads();
    }
  }
  for (int u = t; u < 4096; u += 1024) keys[base + u] = s[u];
}

__global__ void k_sort_global(unsigned long long* keys, int k, int j,
                              const unsigned int* __restrict__ cntp) {
  if (*cntp <= (unsigned)(k >> 1)) return;
  int m = blockIdx.x * 256 + threadIdx.x;
  int i = ((m & ~(j - 1)) << 1) | (m & (j - 1));
  int l = i | j;
  bool dir = ((i & k) == 0);
  unsigned long long A = keys[i], B = keys[l];
  bool sw = dir ? (A < B) : (A > B);
  if (sw) { keys[i] = B; keys[l] = A; }
}

__global__ __launch_bounds__(1024) void k_sort_localmerge(unsigned long long* keys, int k,
                                                          const unsigned int* __restrict__ cntp) {
  if (*cntp <= (unsigned)(k >> 1)) return;
  __shared__ unsigned long long s[4096];
  const int base = blockIdx.x * 4096, t = threadIdx.x;
  for (int u = t; u < 4096; u += 1024) s[u] = keys[base + u];
  __syncthreads();
  const bool dir = ((base & k) == 0);
  for (int j = 2048; j >= 1; j >>= 1) {
    for (int m = t; m < 2048; m += 1024) {
      int i = ((m & ~(j - 1)) << 1) | (m & (j - 1));
      int l = i | j;
      unsigned long long A = s[i], B = s[l];
      bool sw = dir ? (A < B) : (A > B);
      if (sw) { s[i] = B; s[l] = A; }
    }
    __syncthreads();
  }
  for (int u = t; u < 4096; u += 1024) keys[base + u] = s[u];
}

// ---------- gather sorted top-TOPM boxes ----------
__global__ void k_gather(const unsigned long long* __restrict__ keys,
                         const float4* __restrict__ boxes,
                         float4* __restrict__ sbox, unsigned int* __restrict__ sidx,
                         const unsigned int* __restrict__ cntp) {
  int p = blockIdx.x * 256 + threadIdx.x;
  if (p >= TOPM) return;
  unsigned c = *cntp;
  if (p < (int)c) {
    unsigned a = 0xFFFFFFFFu - (unsigned)(keys[p] & 0xFFFFFFFFull);
    sbox[p] = boxes[a];
    sidx[p] = a;
  } else {
    sbox[p] = make_float4(3e9f, 3e9f, 3e9f, 3e9f);
    sidx[p] = 0u;
  }
}

// ---------- pairwise suppression mask: TOPM x TOPM bits (upper triangle) ----------
__global__ __launch_bounds__(256) void k_mask(const float4* __restrict__ sbox,
                                              unsigned long long* __restrict__ mask) {
  if ((int)(blockIdx.y * 8 + 7) < (int)blockIdx.x) return;
  __shared__ float4 jb[512];
  const int i0 = blockIdx.x * 64;
  const int j0 = blockIdx.y * 512;
  const int t = threadIdx.x;
  for (int u = t; u < 512; u += 256) jb[u] = sbox[j0 + u];
  __syncthreads();
  const int il = t & 63, grp = t >> 6;
  const int i = i0 + il;
  const float4 bi = sbox[i];
#pragma unroll
  for (int wwi = 0; wwi < 2; wwi++) {
    int w = grp * 2 + wwi;
    unsigned long long bits = 0ull;
    for (int b = 0; b < 64; b++) {
      if (iou_gt07(bi, jb[w * 64 + b])) bits |= (1ull << b);
    }
    mask[(size_t)i * (TOPM / 64) + (j0 >> 6) + w] = bits;
  }
}

// ---------- phase A sweep: exact greedy via mask rows (wave-parallel, writes abox inline) ----------
__global__ __launch_bounds__(1024) void k_sweepA(const unsigned int* __restrict__ sidx,
                                                 const float4* __restrict__ sbox,
                                                 const unsigned long long* __restrict__ mask,
                                                 unsigned int* __restrict__ ctrs,
                                                 unsigned int* __restrict__ acc,
                                                 float4* __restrict__ abox) {
  __shared__ unsigned long long removed[TOPM / 64];
  __shared__ unsigned long long selfm[2][64];
  __shared__ unsigned int sidxw[2][64];
  __shared__ unsigned char saccb[64];
  __shared__ unsigned int snacc, sna;
  const int t = threadIdx.x;
  const unsigned cnt = ctrs[0];
  const unsigned M = cnt < TOPM ? cnt : TOPM;
  const unsigned nwords = (M + 63u) >> 6;
  if (t < TOPM / 64) removed[t] = 0ull;
  if (t == 0) { sna = 0u; snacc = 0u; }
  if (nwords > 0 && t < 64) {
    selfm[0][t] = mask[(size_t)t * (TOPM / 64) + 0];
    sidxw[0][t] = sidx[t];
  }
  __syncthreads();
  for (unsigned wi = 0; wi < nwords; wi++) {
    const int cur = (int)(wi & 1u);
    if (t < 64) {
      unsigned long long myrow = selfm[cur][t];
      unsigned myidx = sidxw[cur][t];
      unsigned rem0 = M - wi * 64u;
      unsigned long long valid = (rem0 >= 64u) ? ~0ull : ((1ull << rem0) - 1ull);
      unsigned long long w = ~removed[wi] & valid;
      const unsigned na0 = sna;
      unsigned long long accbits = 0ull;
      unsigned n = 0u;
      while (w && (na0 + n) < MAXOUT) {
        int b = __builtin_ctzll(w);
        accbits |= (1ull << b);
        n++;
        unsigned long long row = __shfl(myrow, b);
        w &= ~row;
        w &= ~(1ull << b);
      }
      if ((accbits >> t) & 1ull) {
        unsigned rank = (unsigned)__popcll(accbits & ((t == 0) ? 0ull : ((1ull << t) - 1ull)));
        saccb[rank] = (unsigned char)t;
        acc[na0 + rank] = myidx;
        abox[na0 + rank] = sbox[wi * 64u + (unsigned)t];
      }
      if (t == 0) { snacc = n; sna = na0 + n; }
    }
    __syncthreads();
    if (wi + 1u < nwords && t < 64) {
      selfm[cur ^ 1][t] = mask[(size_t)((wi + 1u) * 64u + t) * (TOPM / 64) + (wi + 1u)];
      sidxw[cur ^ 1][t] = sidx[(wi + 1u) * 64u + t];
    }
    {
      const unsigned nacc = snacc;
      const int wj = t & 127, g = t >> 7;
      if (nacc && (unsigned)g < nacc && wj > (int)wi) {
        unsigned long long a0 = 0ull, a1 = 0ull;
        unsigned k2 = (unsigned)g;
        for (; k2 + 8u < nacc; k2 += 16u) {
          a0 |= mask[(size_t)(wi * 64u + saccb[k2]) * (TOPM / 64) + wj];
          a1 |= mask[(size_t)(wi * 64u + saccb[k2 + 8u]) * (TOPM / 64) + wj];
        }
        for (; k2 < nacc; k2 += 8u)
          a0 |= mask[(size_t)(wi * 64u + saccb[k2]) * (TOPM / 64) + wj];
        unsigned long long accum = a0 | a1;
        if (accum) atomicOr(&removed[wj], accum);
      }
    }
    __syncthreads();
    if (sna >= MAXOUT) break;
  }
  if (t == 0) ctrs[1] = sna;
}

// ---------- grid-parallel filter ----------
__global__ __launch_bounds__(256) void k_filter(const unsigned long long* __restrict__ keys,
                                                const float4* __restrict__ boxes,
                                                const unsigned int* __restrict__ ctrs,
                                                const float4* __restrict__ abox,
                                                unsigned char* __restrict__ flags) {
  __shared__ float4 at[256];
  const int t = threadIdx.x;
  const unsigned cnt = ctrs[0], naA = ctrs[1];
  if (naA >= MAXOUT) return;
  const unsigned q = TOPM + blockIdx.x * 256 + t;
  float4 bq = make_float4(3e9f, 3e9f, 3e9f, 3e9f);
  unsigned flag = 0u;
  if (q < cnt) {
    unsigned a = 0xFFFFFFFFu - (unsigned)(keys[q] & 0xFFFFFFFFull);
    bq = boxes[a];
    flag = 1u;
  }
  for (unsigned u0 = 0; u0 < naA; u0 += 256u) {
    unsigned m = naA - u0; if (m > 256u) m = 256u;
    if ((unsigned)t < m) at[t] = abox[u0 + t];
    __syncthreads();
    if (flag) {
      for (unsigned u = 0; u < m; u++)
        if (iou_gt07(at[u], bq)) { flag = 0u; break; }
    }
    __syncthreads();
  }
  if (q < cnt) flags[q - TOPM] = (unsigned char)flag;
}

// ---------- stable compaction of surviving suffix candidates ----------
__global__ __launch_bounds__(1024) void k_compact(const unsigned long long* __restrict__ keys,
                                                  unsigned int* __restrict__ ctrs,
                                                  const unsigned char* __restrict__ flags,
                                                  unsigned int* __restrict__ said) {
  __shared__ unsigned wsum[16], wpre[16];
  __shared__ unsigned base, tot;
  const int t = threadIdx.x, wid = t >> 6, lane = t & 63;
  const unsigned cnt = ctrs[0], naA = ctrs[1];
  if (naA >= MAXOUT || cnt <= TOPM) { if (t == 0) ctrs[2] = 0u; return; }
  const unsigned n = cnt - TOPM;
  if (t == 0) base = 0u;
  __syncthreads();
  for (unsigned s = 0; s < n; s += 1024u) {
    unsigned q = s + t;
    bool pred = (q < n) && flags[q];
    unsigned long long ball = __ballot(pred);
    if (lane == 0) wsum[wid] = (unsigned)__popcll(ball);
    __syncthreads();
    if (t == 0) {
      unsigned a2 = 0;
      for (int i = 0; i < 16; i++) { wpre[i] = a2; a2 += wsum[i]; }
      tot = a2;
    }
    __syncthreads();
    if (pred) {
      unsigned pos = base + wpre[wid] +
                     (unsigned)__popcll(ball & ((lane == 0) ? 0ull : ((1ull << lane) - 1ull)));
      said[pos] = 0xFFFFFFFFu - (unsigned)(keys[TOPM + q] & 0xFFFFFFFFull);
    }
    __syncthreads();
    if (t == 0) base += tot;
    __syncthreads();
  }
  if (t == 0) ctrs[2] = base;
}

// ---------- phase B: resume chunked greedy over survivors ----------
__global__ __launch_bounds__(256) void k_nmsB(const unsigned int* __restrict__ said,
                                              const float4* __restrict__ boxes,
                                              unsigned int* __restrict__ ctrs,
                                              unsigned int* __restrict__ acc) {
  __shared__ float4 ab[MAXOUT];
  __shared__ float4 cb[64];
  __shared__ unsigned int cba[64];
  __shared__ unsigned long long selfm[64];
  __shared__ unsigned long long ssup;
  __shared__ unsigned int sna;
  const int t = threadIdx.x;
  const unsigned naA = ctrs[1], scnt = ctrs[2];
  if (naA >= MAXOUT || scnt == 0u) return;
  if (t == 0) sna = 0u;
  __syncthreads();
  for (unsigned q0 = 0; q0 < scnt; q0 += 64) {
    unsigned nr = scnt - q0; if (nr > 64u) nr = 64u;
    if (t < 64) {
      if ((unsigned)t < nr) {
        unsigned a = said[q0 + t];
        cba[t] = a;
        cb[t] = boxes[a];
      } else {
        cb[t] = make_float4(3e9f, 3e9f, 3e9f, 3e9f);
        cba[t] = 0u;
      }
    }
    if (t == 0) ssup = 0ull;
    __syncthreads();
    if (t < 64) {
      float4 bi = cb[t];
      unsigned long long bits = 0ull;
      for (int b = 0; b < 64; b++)
        if (iou_gt07(bi, cb[b])) bits |= (1ull << b);
      selfm[t] = bits;
    }
    const unsigned na0 = sna;
    unsigned long long mybits = 0ull;
    const int colg = (t & 3) * 16;
    for (unsigned u = (unsigned)(t >> 2); u < na0; u += 64u) {
      float4 au = ab[u];
#pragma unroll
      for (int b2 = 0; b2 < 16; b2++)
        if (iou_gt07(au, cb[colg + b2])) mybits |= (1ull << (colg + b2));
    }
    if (mybits) atomicOr(&ssup, mybits);
    __syncthreads();
    if (t == 0) {
      unsigned long long w = ~ssup;
      if (nr < 64u) w &= ((1ull << nr) - 1ull);
      unsigned na = sna;
      while (w && (naA + na) < MAXOUT) {
        int b = __builtin_ctzll(w);
        ab[na] = cb[b];
        acc[naA + na] = cba[b];
        na++;
        w &= ~selfm[b];
      }
      sna = na;
    }
    __syncthreads();
    if (naA + sna >= MAXOUT) break;
  }
  if (t == 0) ctrs[1] = naA + sna;
}

// ---------- write outputs (f32) ----------
__global__ void k_output(const float4* __restrict__ boxes, const float* __restrict__ score,
                         const unsigned int* __restrict__ acc, const unsigned int* __restrict__ ctrs,
                         float* __restrict__ out) {
  int tdx = blockIdx.x * 256 + threadIdx.x;
  if (tdx >= MAXOUT) return;
  unsigned na = ctrs[1];
  float4 b = make_float4(0.f, 0.f, 0.f, 0.f);
  float o0 = 0.f, o1 = 0.f;
  if (tdx < (int)na) {
    unsigned a = acc[tdx];
    b = boxes[a];
    o0 = score[2 * (size_t)a];
    o1 = score[2 * (size_t)a + 1];
  }
  out[tdx * 4 + 0] = b.x;
  out[tdx * 4 + 1] = b.y;
  out[tdx * 4 + 2] = b.z;
  out[tdx * 4 + 3] = b.w;
  out[8000 + tdx * 2 + 0] = o0;
  out[8000 + tdx * 2 + 1] = o1;
}

// ---------- diagnostic probe ----------
__global__ __launch_bounds__(256) void k_probe(const float* __restrict__ h,
                                               const float* __restrict__ score,
                                               const unsigned long long* __restrict__ keys,
                                               const unsigned int* __restrict__ ctrs,
                                               float* __restrict__ out) {
  __shared__ unsigned sf;
  const int t = threadIdx.x;
  if (t == 0) sf = 0u;
  __syncthreads();
  unsigned local = 0u;
  for (int i = t; i < 4096; i += 256)
    if (h[(size_t)i * 575] > 0.f) { local |= 1u; break; }
  for (int i = t; i < 4096; i += 256)
    if (score[(size_t)i * 40] > 0.2f) { local |= 2u; break; }
  if (t == 0) {
    unsigned cnt = ctrs[0], na = ctrs[1];
    if (cnt > 0u)                local |= 4u;
    if (cnt >= 4096u)            local |= 8u;
    if ((keys[0] >> 32) != 0ull) local |= 16u;
    if (na >= 1u)                local |= 32u;
  }
  atomicOr(&sf, local);
  __syncthreads();
  if (t == 0 && (sf & 63u) != 63u) out[0] = 1e6f * (1.f + (float)sf);
}

extern "C" void kernel_launch(void* const* d_in, const int* in_sizes, int n_in,
                              void* d_out, int out_size, void* d_ws, size_t ws_size,
                              hipStream_t stream) {
  const float* x       = (const float*)d_in[0];
  const float* conv_w  = (const float*)d_in[1];
  const float* conv_b  = (const float*)d_in[2];
  const float* bbox_w  = (const float*)d_in[3];
  const float* bbox_b  = (const float*)d_in[4];
  const float* score_w = (const float*)d_in[5];
  const float* score_b = (const float*)d_in[6];

  char* ws = (char*)d_ws;
  size_t off = 0;
  auto alloc = [&](size_t bytes) {
    void* p = ws + off;
    off = (off + bytes + 255) & ~(size_t)255;
    return p;
  };
  float* h = (float*)alloc((size_t)256 * SGRID * 4);          // 9.44 MB, alive whole run
  char*  R = (char*)alloc((size_t)13292544 + 512);            // union region
  // early views (dead after k_conv3)
  float* xpad = (float*)R;                                    // 256*98*104*4 = 10,446,848
  float* wre  = (float*)(R + 10446848);                       // 2,359,296 (ends 12,806,144)
  // late views (born after k_conv3)
  float* bbox              = (float*)(R + 0);                 // 1,327,104
  float* score             = (float*)(R + 1327104);           //   663,552
  float4* boxes            = (float4*)(R + 1990656);          // 1,327,104
  unsigned long long* keys = (unsigned long long*)(R + 3317760); // 1,048,576
  float4* sbox             = (float4*)(R + 4366336);          //   131,072
  unsigned int* sidx       = (unsigned int*)(R + 4497408);    //    32,768
  unsigned long long* mask = (unsigned long long*)(R + 4530176); // 8,388,608
  unsigned char* flags     = (unsigned char*)(R + 12918784);  //    74,752
  unsigned int* said       = (unsigned int*)(R + 12993536);   //   299,008 (ends 13,292,544)
  unsigned int* acc        = (unsigned int*)alloc((size_t)2048 * 4);
  float4* abox             = (float4*)alloc((size_t)2048 * 16);
  unsigned int* ctrs       = (unsigned int*)alloc(64);
  unsigned int* cnt = ctrs + 0;
  (void)in_sizes; (void)n_in; (void)out_size; (void)ws_size;

  k_pad<<<2048, 256, 0, stream>>>(x, xpad);
  k_wre<<<1024, 256, 0, stream>>>(conv_w, wre);
  k_conv3<<<dim3(96, 256 / OCB), 128, 0, stream>>>(xpad, wre, conv_b, h);

  k_init<<<NSORT / 256, 256, 0, stream>>>(keys, ctrs);
  k_conv1x1<<<dim3(36, 3), 256, 0, stream>>>(h, bbox_w, bbox_b, score_w, score_b, bbox, score);
  k_decode<<<NANCH / 256, 256, 0, stream>>>(bbox, score, boxes, keys, cnt);

  k_sort_local<<<NSORT / 4096, 1024, 0, stream>>>(keys, cnt);
  for (int k = 8192; k <= NSORT; k <<= 1) {
    for (int j = k >> 1; j >= 4096; j >>= 1)
      k_sort_global<<<NSORT / 512, 256, 0, stream>>>(keys, k, j, cnt);
    k_sort_localmerge<<<NSORT / 4096, 1024, 0, stream>>>(keys, k, cnt);
  }

  k_gather<<<TOPM / 256, 256, 0, stream>>>(keys, boxes, sbox, sidx, cnt);
  k_mask<<<dim3(TOPM / 64, TOPM / 512), 256, 0, stream>>>(sbox, mask);
  k_sweepA<<<1, 1024, 0, stream>>>(sidx, sbox, mask, ctrs, acc, abox);

  k_filter<<<(NANCH - TOPM + 255) / 256, 256, 0, stream>>>(keys, boxes, ctrs, abox, flags);
  k_compact<<<1, 1024, 0, stream>>>(keys, ctrs, flags, said);
  k_nmsB<<<1, 256, 0, stream>>>(said, boxes, ctrs, acc);

  k_output<<<(MAXOUT + 255) / 256, 256, 0, stream>>>(boxes, score, acc, ctrs, (float*)d_out);
  k_probe<<<1, 256, 0, stream>>>(h, score, keys, ctrs, (float*)d_out);
}

// Round 19
// 779.020 us; speedup vs baseline: 1.0879x; 1.0879x over previous
//
#include <hip/hip_runtime.h>
#include <hip/hip_bf16.h>
#include <math.h>

#define SGRID 9216      // 96*96
#define NANCH 82944     // 9216*9
#define NSORT 131072    // pow2 >= worst-case candidate count (82944)
#define TOPM  8192      // phase-A window (sorted prefix)
#define MAXOUT 2000
#define OCB 16
#define XPS 104         // xpad row stride (float4-aligned)
#define XCS (98 * XPS)  // xpad channel stride = 10192

// ---------- helpers ----------
__device__ __forceinline__ bool iou_gt07(const float4 bi, const float4 bj) {
  float a1 = __fmul_rn(bi.z - bi.x, bi.w - bi.y);
  float a2 = __fmul_rn(bj.z - bj.x, bj.w - bj.y);
  float xx1 = fmaxf(bi.x, bj.x), yy1 = fmaxf(bi.y, bj.y);
  float xx2 = fminf(bi.z, bj.z), yy2 = fminf(bi.w, bj.w);
  float inter = __fmul_rn(fmaxf(xx2 - xx1, 0.f), fmaxf(yy2 - yy1, 0.f));
  float den = ((a1 + a2) - inter) + 1e-9f;
  return __fdiv_rn(inter, den) > 0.7f;
}

// ---------- init ----------
__global__ void k_init(unsigned long long* keys, unsigned int* ctrs) {
  int i = blockIdx.x * 256 + threadIdx.x;
  if (i < NSORT) keys[i] = 0ull;
  if (i < 8) ctrs[i] = 0u;
}

// ---------- pad x into [256][98][104] (zero border, stride 104) ----------
__global__ void k_pad(const float* __restrict__ x, float* __restrict__ xpad) {
  for (size_t i = (size_t)blockIdx.x * 256 + threadIdx.x; i < (size_t)256 * XCS;
       i += (size_t)gridDim.x * 256) {
    int ic = (int)(i / XCS);
    int rem = (int)(i % XCS);
    int yy = rem / XPS, xx = rem % XPS;
    float v = 0.f;
    if (yy >= 1 && yy <= 96 && xx >= 1 && xx <= 96)
      v = x[(size_t)ic * SGRID + (yy - 1) * 96 + (xx - 1)];
    xpad[i] = v;
  }
}

// ---------- reorder weights into [32 chunk][256 oc][72] ----------
__global__ void k_wre(const float* __restrict__ w, float* __restrict__ wre) {
  for (size_t i = (size_t)blockIdx.x * 256 + threadIdx.x; i < (size_t)32 * 256 * 72;
       i += (size_t)gridDim.x * 256) {
    int c = (int)(i / (256 * 72));
    int rem = (int)(i % (256 * 72));
    int oc = rem / 72, j = rem % 72;
    wre[i] = w[(size_t)oc * 2304 + c * 72 + j];
  }
}

// ---------- conv 3x3 (256->256, SAME, relu): reg-dbuf, 1 barrier/chunk, OCB=16 ----------
// grid (96 rows, 16 oc-groups of 16), block 256: og = t>>4 (1 oc each), xg = t&15 (6 x each)
__global__ __launch_bounds__(256) void k_conv3(const float* __restrict__ xpad,
                                               const float* __restrict__ wre,
                                               const float* __restrict__ bias,
                                               float* __restrict__ h) {
  __shared__ float xsB[2][8][320];   // 8 ic x (3 rows x 104)
  __shared__ float wB[2][1152];      // 16 oc x 72
  const int y = blockIdx.x;
  const int oc0 = blockIdx.y * OCB;
  const int t = threadIdx.x;
  const int og = t >> 4;             // 16 groups of 1 oc
  const int xg = t & 15;             // 16 groups of 6 x
  float acc[6];
#pragma unroll
  for (int c = 0; c < 6; c++) acc[c] = 0.f;

  int xg_ofs[3], xl_ofs[3];
  bool xon[3];
#pragma unroll
  for (int k = 0; k < 3; k++) {
    int idx = t + k * 256;
    xon[k] = (idx < 624);
    int rowidx = idx / 26, col = idx - rowidx * 26;
    int ic = rowidx / 3, r = rowidx - ic * 3;
    if (!xon[k]) { ic = 0; r = 0; col = 0; }
    xg_ofs[k] = ic * XCS + (y + r) * XPS + col * 4;
    xl_ofs[k] = ic * 320 + r * XPS + col * 4;
  }
  bool won[2];
#pragma unroll
  for (int k = 0; k < 2; k++) won[k] = ((t + k * 256) < 288);

  float4 xv[3], wv[2];
  auto ldreg = [&](int c) {
    const float* xb = xpad + (size_t)c * 8 * XCS;
    const float* wb = wre + ((size_t)c * 256 + oc0) * 72;
#pragma unroll
    for (int k = 0; k < 3; k++)
      if (xon[k]) xv[k] = *(const float4*)(xb + xg_ofs[k]);
#pragma unroll
    for (int k = 0; k < 2; k++)
      if (won[k]) wv[k] = *(const float4*)(wb + (t + k * 256) * 4);
  };
  auto stlds = [&](int buf) {
    float* xd = &xsB[buf][0][0];
#pragma unroll
    for (int k = 0; k < 3; k++)
      if (xon[k]) *(float4*)(xd + xl_ofs[k]) = xv[k];
#pragma unroll
    for (int k = 0; k < 2; k++)
      if (won[k]) *(float4*)(&wB[buf][(t + k * 256) * 4]) = wv[k];
  };

  ldreg(0);
  stlds(0);
  ldreg(1);
  __syncthreads();
  int buf = 0;
  for (int c = 0; c < 32; c++) {
    if (c < 31) {
      stlds(buf ^ 1);
      if (c < 30) ldreg(c + 2);
    }
#pragma unroll
    for (int ic = 0; ic < 8; ic++) {
#pragma unroll
      for (int r = 0; r < 3; r++) {
        float xr[8];
#pragma unroll
        for (int u = 0; u < 8; u++) xr[u] = xsB[buf][ic][r * XPS + xg * 6 + u];
        float w0 = wB[buf][og * 72 + ic * 9 + r * 3 + 0];
        float w1 = wB[buf][og * 72 + ic * 9 + r * 3 + 1];
        float w2 = wB[buf][og * 72 + ic * 9 + r * 3 + 2];
#pragma unroll
        for (int c2 = 0; c2 < 6; c2++)
          acc[c2] += xr[c2] * w0 + xr[c2 + 1] * w1 + xr[c2 + 2] * w2;
      }
    }
    __syncthreads();
    buf ^= 1;
  }
  {
    int oc = oc0 + og;
    float bb = bias[oc];
#pragma unroll
    for (int c = 0; c < 6; c++) {
      float v = acc[c] + bb;
      h[(size_t)oc * SGRID + y * 96 + xg * 6 + c] = v > 0.f ? v : 0.f;
    }
  }
}

// ---------- 1x1 heads: channel-split, grid (36 pos-groups, 3 ch-groups of 18) ----------
__global__ __launch_bounds__(256) void k_conv1x1(const float* __restrict__ h,
                                                 const float* __restrict__ bw, const float* __restrict__ bb,
                                                 const float* __restrict__ sw, const float* __restrict__ sb,
                                                 float* __restrict__ bbox, float* __restrict__ score) {
  __shared__ float wcat[18][256];
  const int t = threadIdx.x;
  const int cg = blockIdx.y;
  for (int idx = t; idx < 18 * 64; idx += 256) {
    int cl = idx >> 6, k4 = idx & 63;
    int c = cg * 18 + cl;
    const float* src = (c < 36) ? (bw + c * 256) : (sw + (c - 36) * 256);
    float4 v = *(const float4*)(src + k4 * 4);
    *(float4*)(&wcat[cl][k4 * 4]) = v;
  }
  __syncthreads();
  const int p = blockIdx.x * 256 + t;
  float accA[18];
#pragma unroll
  for (int cl = 0; cl < 18; cl++) accA[cl] = 0.f;
  for (int k0 = 0; k0 < 256; k0 += 8) {
    float ha[8];
#pragma unroll
    for (int u = 0; u < 8; u++) ha[u] = h[(size_t)(k0 + u) * SGRID + p];
#pragma unroll
    for (int cl = 0; cl < 18; cl++) {
      float4 w0 = *(const float4*)(&wcat[cl][k0]);
      float4 w1 = *(const float4*)(&wcat[cl][k0 + 4]);
      accA[cl] += ha[0] * w0.x + ha[1] * w0.y + ha[2] * w0.z + ha[3] * w0.w
                + ha[4] * w1.x + ha[5] * w1.y + ha[6] * w1.z + ha[7] * w1.w;
    }
  }
#pragma unroll
  for (int cl = 0; cl < 18; cl++) {
    int c = cg * 18 + cl;
    if (c < 36) {
      float va = accA[cl] + bb[c];
      bbox[(size_t)c * SGRID + p] = va > 0.f ? va : 0.f;
    } else {
      float va = accA[cl] + sb[c - 36];
      score[(size_t)(c - 36) * SGRID + p] = va > 0.f ? va : 0.f;
    }
  }
}

// ---------- decode + filter + candidate compaction ----------
__global__ void k_decode(const float* __restrict__ bbox, const float* __restrict__ score,
                         float4* __restrict__ boxes, unsigned long long* __restrict__ keys,
                         unsigned int* __restrict__ cnt) {
  int a = blockIdx.x * 256 + threadIdx.x;
  if (a >= NANCH) return;
  int i = a / 864;
  int rem = a - i * 864;
  int j = rem / 9;
  int k = rem - j * 9;
  const double areas[3] = {16384.0, 65536.0, 262144.0};
  int ai = k / 3, ri = k - ai * 3;
  double wr = (ri == 1) ? 2.0 : 1.0;
  double hr = (ri == 2) ? 2.0 : 1.0;
  double u = sqrt(areas[ai] / (wr * hr));
  double wd = wr * u, hd = hr * u;
  double cxd = (i + 0.5) * 16.0, cyd = (j + 0.5) * 16.0;
  float ax1 = (float)(cxd - wd * 0.5), ax2 = (float)(cxd + wd * 0.5);
  float ay1 = (float)(cyd - hd * 0.5), ay2 = (float)(cyd + hd * 0.5);
  float wa = ax2 - ax1, haa = ay2 - ay1;
  float cxa = (ax1 + ax2) * 0.5f, cya = (ay1 + ay2) * 0.5f;

  float4 br = ((const float4*)bbox)[a];
  float o0 = score[2 * (size_t)a];

  float cx = __fmul_rn(br.x, wa) + cxa;
  float cy = __fmul_rn(br.y, haa) + cya;
  float ww = __fmul_rn(expf(br.z), wa);
  float hh = __fmul_rn(expf(br.w), haa);
  float x1 = fminf(fmaxf(cx - __fmul_rn(ww, 0.5f), 0.f), 1536.f);
  float y1 = fminf(fmaxf(cy - __fmul_rn(hh, 0.5f), 0.f), 1536.f);
  float x2 = fminf(fmaxf(cx + __fmul_rn(ww, 0.5f), 0.f), 1536.f);
  float y2 = fminf(fmaxf(cy + __fmul_rn(hh, 0.5f), 0.f), 1536.f);
  boxes[a] = make_float4(x1, y1, x2, y2);
  float area = fabsf(__fmul_rn(x1 - x2, y1 - y2));
  if (o0 > 0.2f && area > 100.0f) {
    unsigned p = atomicAdd(cnt, 1u);
    keys[p] = ((unsigned long long)__float_as_uint(o0) << 32) |
              (unsigned long long)(0xFFFFFFFFu - (unsigned)a);
  }
}

// ---------- bitonic sort (descending), cnt-aware stage skipping ----------
__global__ __launch_bounds__(1024) void k_sort_local(unsigned long long* keys,
                                                     const unsigned int* __restrict__ cntp) {
  __shared__ unsigned long long s[4096];
  const int base = blockIdx.x * 4096, t = threadIdx.x;
  if ((unsigned)base >= *cntp) return;
  for (int u = t; u < 4096; u += 1024) s[u] = keys[base + u];
  __syncthreads();
  for (int k = 2; k <= 4096; k <<= 1) {
    for (int j = k >> 1; j >= 1; j >>= 1) {
      for (int m = t; m < 2048; m += 1024) {
        int i = ((m & ~(j - 1)) << 1) | (m & (j - 1));
        int l = i | j;
        bool dir = (((base + i) & k) == 0);
        unsigned long long A = s[i], B = s[l];
        bool sw = dir ? (A < B) : (A > B);
        if (sw) { s[i] = B; s[l] = A; }
      }
      __syncthreads();
    }
  }
  for (int u = t; u < 4096; u += 1024) keys[base + u] = s[u];
}

__global__ void k_sort_global(unsigned long long* keys, int k, int j,
                              const unsigned int* __restrict__ cntp) {
  if (*cntp <= (unsigned)(k >> 1)) return;
  int m = blockIdx.x * 256 + threadIdx.x;
  int i = ((m & ~(j - 1)) << 1) | (m & (j - 1));
  int l = i | j;
  bool dir = ((i & k) == 0);
  unsigned long long A = keys[i], B = keys[l];
  bool sw = dir ? (A < B) : (A > B);
  if (sw) { keys[i] = B; keys[l] = A; }
}

__global__ __launch_bounds__(1024) void k_sort_localmerge(unsigned long long* keys, int k,
                                                          const unsigned int* __restrict__ cntp) {
  if (*cntp <= (unsigned)(k >> 1)) return;
  __shared__ unsigned long long s[4096];
  const int base = blockIdx.x * 4096, t = threadIdx.x;
  for (int u = t; u < 4096; u += 1024) s[u] = keys[base + u];
  __syncthreads();
  const bool dir = ((base & k) == 0);
  for (int j = 2048; j >= 1; j >>= 1) {
    for (int m = t; m < 2048; m += 1024) {
      int i = ((m & ~(j - 1)) << 1) | (m & (j - 1));
      int l = i | j;
      unsigned long long A = s[i], B = s[l];
      bool sw = dir ? (A < B) : (A > B);
      if (sw) { s[i] = B; s[l] = A; }
    }
    __syncthreads();
  }
  for (int u = t; u < 4096; u += 1024) keys[base + u] = s[u];
}

// ---------- gather sorted top-TOPM boxes ----------
__global__ void k_gather(const unsigned long long* __restrict__ keys,
                         const float4* __restrict__ boxes,
                         float4* __restrict__ sbox, unsigned int* __restrict__ sidx,
                         const unsigned int* __restrict__ cntp) {
  int p = blockIdx.x * 256 + threadIdx.x;
  if (p >= TOPM) return;
  unsigned c = *cntp;
  if (p < (int)c) {
    unsigned a = 0xFFFFFFFFu - (unsigned)(keys[p] & 0xFFFFFFFFull);
    sbox[p] = boxes[a];
    sidx[p] = a;
  } else {
    sbox[p] = make_float4(3e9f, 3e9f, 3e9f, 3e9f);
    sidx[p] = 0u;
  }
}

// ---------- pairwise suppression mask: TOPM x TOPM bits (upper triangle) ----------
__global__ __launch_bounds__(256) void k_mask(const float4* __restrict__ sbox,
                                              unsigned long long* __restrict__ mask) {
  if ((int)(blockIdx.y * 8 + 7) < (int)blockIdx.x) return;
  __shared__ float4 jb[512];
  const int i0 = blockIdx.x * 64;
  const int j0 = blockIdx.y * 512;
  const int t = threadIdx.x;
  for (int u = t; u < 512; u += 256) jb[u] = sbox[j0 + u];
  __syncthreads();
  const int il = t & 63, grp = t >> 6;
  const int i = i0 + il;
  const float4 bi = sbox[i];
#pragma unroll
  for (int wwi = 0; wwi < 2; wwi++) {
    int w = grp * 2 + wwi;
    unsigned long long bits = 0ull;
    for (int b = 0; b < 64; b++) {
      if (iou_gt07(bi, jb[w * 64 + b])) bits |= (1ull << b);
    }
    mask[(size_t)i * (TOPM / 64) + (j0 >> 6) + w] = bits;
  }
}

// ---------- phase A sweep: exact greedy via mask rows (wave-parallel, writes abox inline) ----------
__global__ __launch_bounds__(1024) void k_sweepA(const unsigned int* __restrict__ sidx,
                                                 const float4* __restrict__ sbox,
                                                 const unsigned long long* __restrict__ mask,
                                                 unsigned int* __restrict__ ctrs,
                                                 unsigned int* __restrict__ acc,
                                                 float4* __restrict__ abox) {
  __shared__ unsigned long long removed[TOPM / 64];
  __shared__ unsigned long long selfm[2][64];
  __shared__ unsigned int sidxw[2][64];
  __shared__ unsigned char saccb[64];
  __shared__ unsigned int snacc, sna;
  const int t = threadIdx.x;
  const unsigned cnt = ctrs[0];
  const unsigned M = cnt < TOPM ? cnt : TOPM;
  const unsigned nwords = (M + 63u) >> 6;
  if (t < TOPM / 64) removed[t] = 0ull;
  if (t == 0) { sna = 0u; snacc = 0u; }
  if (nwords > 0 && t < 64) {
    selfm[0][t] = mask[(size_t)t * (TOPM / 64) + 0];
    sidxw[0][t] = sidx[t];
  }
  __syncthreads();
  for (unsigned wi = 0; wi < nwords; wi++) {
    const int cur = (int)(wi & 1u);
    if (t < 64) {
      unsigned long long myrow = selfm[cur][t];
      unsigned myidx = sidxw[cur][t];
      unsigned rem0 = M - wi * 64u;
      unsigned long long valid = (rem0 >= 64u) ? ~0ull : ((1ull << rem0) - 1ull);
      unsigned long long w = ~removed[wi] & valid;
      const unsigned na0 = sna;
      unsigned long long accbits = 0ull;
      unsigned n = 0u;
      while (w && (na0 + n) < MAXOUT) {
        int b = __builtin_ctzll(w);
        accbits |= (1ull << b);
        n++;
        unsigned long long row = __shfl(myrow, b);
        w &= ~row;
        w &= ~(1ull << b);
      }
      if ((accbits >> t) & 1ull) {
        unsigned rank = (unsigned)__popcll(accbits & ((t == 0) ? 0ull : ((1ull << t) - 1ull)));
        saccb[rank] = (unsigned char)t;
        acc[na0 + rank] = myidx;
        abox[na0 + rank] = sbox[wi * 64u + (unsigned)t];
      }
      if (t == 0) { snacc = n; sna = na0 + n; }
    }
    __syncthreads();
    if (wi + 1u < nwords && t < 64) {
      selfm[cur ^ 1][t] = mask[(size_t)((wi + 1u) * 64u + t) * (TOPM / 64) + (wi + 1u)];
      sidxw[cur ^ 1][t] = sidx[(wi + 1u) * 64u + t];
    }
    {
      const unsigned nacc = snacc;
      const int wj = t & 127, g = t >> 7;
      if (nacc && (unsigned)g < nacc && wj > (int)wi) {
        unsigned long long a0 = 0ull, a1 = 0ull;
        unsigned k2 = (unsigned)g;
        for (; k2 + 8u < nacc; k2 += 16u) {
          a0 |= mask[(size_t)(wi * 64u + saccb[k2]) * (TOPM / 64) + wj];
          a1 |= mask[(size_t)(wi * 64u + saccb[k2 + 8u]) * (TOPM / 64) + wj];
        }
        for (; k2 < nacc; k2 += 8u)
          a0 |= mask[(size_t)(wi * 64u + saccb[k2]) * (TOPM / 64) + wj];
        unsigned long long accum = a0 | a1;
        if (accum) atomicOr(&removed[wj], accum);
      }
    }
    __syncthreads();
    if (sna >= MAXOUT) break;
  }
  if (t == 0) ctrs[1] = sna;
}

// ---------- grid-parallel filter ----------
__global__ __launch_bounds__(256) void k_filter(const unsigned long long* __restrict__ keys,
                                                const float4* __restrict__ boxes,
                                                const unsigned int* __restrict__ ctrs,
                                                const float4* __restrict__ abox,
                                                unsigned char* __restrict__ flags) {
  __shared__ float4 at[256];
  const int t = threadIdx.x;
  const unsigned cnt = ctrs[0], naA = ctrs[1];
  if (naA >= MAXOUT) return;
  const unsigned q = TOPM + blockIdx.x * 256 + t;
  float4 bq = make_float4(3e9f, 3e9f, 3e9f, 3e9f);
  unsigned flag = 0u;
  if (q < cnt) {
    unsigned a = 0xFFFFFFFFu - (unsigned)(keys[q] & 0xFFFFFFFFull);
    bq = boxes[a];
    flag = 1u;
  }
  for (unsigned u0 = 0; u0 < naA; u0 += 256u) {
    unsigned m = naA - u0; if (m > 256u) m = 256u;
    if ((unsigned)t < m) at[t] = abox[u0 + t];
    __syncthreads();
    if (flag) {
      for (unsigned u = 0; u < m; u++)
        if (iou_gt07(at[u], bq)) { flag = 0u; break; }
    }
    __syncthreads();
  }
  if (q < cnt) flags[q - TOPM] = (unsigned char)flag;
}

// ---------- stable compaction of surviving suffix candidates ----------
__global__ __launch_bounds__(1024) void k_compact(const unsigned long long* __restrict__ keys,
                                                  unsigned int* __restrict__ ctrs,
                                                  const unsigned char* __restrict__ flags,
                                                  unsigned int* __restrict__ said) {
  __shared__ unsigned wsum[16], wpre[16];
  __shared__ unsigned base, tot;
  const int t = threadIdx.x, wid = t >> 6, lane = t & 63;
  const unsigned cnt = ctrs[0], naA = ctrs[1];
  if (naA >= MAXOUT || cnt <= TOPM) { if (t == 0) ctrs[2] = 0u; return; }
  const unsigned n = cnt - TOPM;
  if (t == 0) base = 0u;
  __syncthreads();
  for (unsigned s = 0; s < n; s += 1024u) {
    unsigned q = s + t;
    bool pred = (q < n) && flags[q];
    unsigned long long ball = __ballot(pred);
    if (lane == 0) wsum[wid] = (unsigned)__popcll(ball);
    __syncthreads();
    if (t == 0) {
      unsigned a2 = 0;
      for (int i = 0; i < 16; i++) { wpre[i] = a2; a2 += wsum[i]; }
      tot = a2;
    }
    __syncthreads();
    if (pred) {
      unsigned pos = base + wpre[wid] +
                     (unsigned)__popcll(ball & ((lane == 0) ? 0ull : ((1ull << lane) - 1ull)));
      said[pos] = 0xFFFFFFFFu - (unsigned)(keys[TOPM + q] & 0xFFFFFFFFull);
    }
    __syncthreads();
    if (t == 0) base += tot;
    __syncthreads();
  }
  if (t == 0) ctrs[2] = base;
}

// ---------- phase B: resume chunked greedy over survivors ----------
__global__ __launch_bounds__(256) void k_nmsB(const unsigned int* __restrict__ said,
                                              const float4* __restrict__ boxes,
                                              unsigned int* __restrict__ ctrs,
                                              unsigned int* __restrict__ acc) {
  __shared__ float4 ab[MAXOUT];
  __shared__ float4 cb[64];
  __shared__ unsigned int cba[64];
  __shared__ unsigned long long selfm[64];
  __shared__ unsigned long long ssup;
  __shared__ unsigned int sna;
  const int t = threadIdx.x;
  const unsigned naA = ctrs[1], scnt = ctrs[2];
  if (naA >= MAXOUT || scnt == 0u) return;
  if (t == 0) sna = 0u;
  __syncthreads();
  for (unsigned q0 = 0; q0 < scnt; q0 += 64) {
    unsigned nr = scnt - q0; if (nr > 64u) nr = 64u;
    if (t < 64) {
      if ((unsigned)t < nr) {
        unsigned a = said[q0 + t];
        cba[t] = a;
        cb[t] = boxes[a];
      } else {
        cb[t] = make_float4(3e9f, 3e9f, 3e9f, 3e9f);
        cba[t] = 0u;
      }
    }
    if (t == 0) ssup = 0ull;
    __syncthreads();
    if (t < 64) {
      float4 bi = cb[t];
      unsigned long long bits = 0ull;
      for (int b = 0; b < 64; b++)
        if (iou_gt07(bi, cb[b])) bits |= (1ull << b);
      selfm[t] = bits;
    }
    const unsigned na0 = sna;
    unsigned long long mybits = 0ull;
    const int colg = (t & 3) * 16;
    for (unsigned u = (unsigned)(t >> 2); u < na0; u += 64u) {
      float4 au = ab[u];
#pragma unroll
      for (int b2 = 0; b2 < 16; b2++)
        if (iou_gt07(au, cb[colg + b2])) mybits |= (1ull << (colg + b2));
    }
    if (mybits) atomicOr(&ssup, mybits);
    __syncthreads();
    if (t == 0) {
      unsigned long long w = ~ssup;
      if (nr < 64u) w &= ((1ull << nr) - 1ull);
      unsigned na = sna;
      while (w && (naA + na) < MAXOUT) {
        int b = __builtin_ctzll(w);
        ab[na] = cb[b];
        acc[naA + na] = cba[b];
        na++;
        w &= ~selfm[b];
      }
      sna = na;
    }
    __syncthreads();
    if (naA + sna >= MAXOUT) break;
  }
  if (t == 0) ctrs[1] = naA + sna;
}

// ---------- write outputs (f32) ----------
__global__ void k_output(const float4* __restrict__ boxes, const float* __restrict__ score,
                         const unsigned int* __restrict__ acc, const unsigned int* __restrict__ ctrs,
                         float* __restrict__ out) {
  int tdx = blockIdx.x * 256 + threadIdx.x;
  if (tdx >= MAXOUT) return;
  unsigned na = ctrs[1];
  float4 b = make_float4(0.f, 0.f, 0.f, 0.f);
  float o0 = 0.f, o1 = 0.f;
  if (tdx < (int)na) {
    unsigned a = acc[tdx];
    b = boxes[a];
    o0 = score[2 * (size_t)a];
    o1 = score[2 * (size_t)a + 1];
  }
  out[tdx * 4 + 0] = b.x;
  out[tdx * 4 + 1] = b.y;
  out[tdx * 4 + 2] = b.z;
  out[tdx * 4 + 3] = b.w;
  out[8000 + tdx * 2 + 0] = o0;
  out[8000 + tdx * 2 + 1] = o1;
}

// ---------- diagnostic probe ----------
__global__ __launch_bounds__(256) void k_probe(const float* __restrict__ h,
                                               const float* __restrict__ score,
                                               const unsigned long long* __restrict__ keys,
                                               const unsigned int* __restrict__ ctrs,
                                               float* __restrict__ out) {
  __shared__ unsigned sf;
  const int t = threadIdx.x;
  if (t == 0) sf = 0u;
  __syncthreads();
  unsigned local = 0u;
  for (int i = t; i < 4096; i += 256)
    if (h[(size_t)i * 575] > 0.f) { local |= 1u; break; }
  for (int i = t; i < 4096; i += 256)
    if (score[(size_t)i * 40] > 0.2f) { local |= 2u; break; }
  if (t == 0) {
    unsigned cnt = ctrs[0], na = ctrs[1];
    if (cnt > 0u)                local |= 4u;
    if (cnt >= 4096u)            local |= 8u;
    if ((keys[0] >> 32) != 0ull) local |= 16u;
    if (na >= 1u)                local |= 32u;
  }
  atomicOr(&sf, local);
  __syncthreads();
  if (t == 0 && (sf & 63u) != 63u) out[0] = 1e6f * (1.f + (float)sf);
}

extern "C" void kernel_launch(void* const* d_in, const int* in_sizes, int n_in,
                              void* d_out, int out_size, void* d_ws, size_t ws_size,
                              hipStream_t stream) {
  const float* x       = (const float*)d_in[0];
  const float* conv_w  = (const float*)d_in[1];
  const float* conv_b  = (const float*)d_in[2];
  const float* bbox_w  = (const float*)d_in[3];
  const float* bbox_b  = (const float*)d_in[4];
  const float* score_w = (const float*)d_in[5];
  const float* score_b = (const float*)d_in[6];

  char* ws = (char*)d_ws;
  size_t off = 0;
  auto alloc = [&](size_t bytes) {
    void* p = ws + off;
    off = (off + bytes + 255) & ~(size_t)255;
    return p;
  };
  float* h = (float*)alloc((size_t)256 * SGRID * 4);          // 9.44 MB, alive whole run
  char*  R = (char*)alloc((size_t)13292544 + 512);            // union region
  // early views (dead after k_conv3)
  float* xpad = (float*)R;                                    // 256*98*104*4 = 10,446,848
  float* wre  = (float*)(R + 10446848);                       // 2,359,296 (ends 12,806,144)
  // late views (born after k_conv3)
  float* bbox              = (float*)(R + 0);                 // 1,327,104
  float* score             = (float*)(R + 1327104);           //   663,552
  float4* boxes            = (float4*)(R + 1990656);          // 1,327,104
  unsigned long long* keys = (unsigned long long*)(R + 3317760); // 1,048,576
  float4* sbox             = (float4*)(R + 4366336);          //   131,072
  unsigned int* sidx       = (unsigned int*)(R + 4497408);    //    32,768
  unsigned long long* mask = (unsigned long long*)(R + 4530176); // 8,388,608
  unsigned char* flags     = (unsigned char*)(R + 12918784);  //    74,752
  unsigned int* said       = (unsigned int*)(R + 12993536);   //   299,008 (ends 13,292,544)
  unsigned int* acc        = (unsigned int*)alloc((size_t)2048 * 4);
  float4* abox             = (float4*)alloc((size_t)2048 * 16);
  unsigned int* ctrs       = (unsigned int*)alloc(64);
  unsigned int* cnt = ctrs + 0;
  (void)in_sizes; (void)n_in; (void)out_size; (void)ws_size;

  k_pad<<<2048, 256, 0, stream>>>(x, xpad);
  k_wre<<<1024, 256, 0, stream>>>(conv_w, wre);
  k_conv3<<<dim3(96, 256 / OCB), 256, 0, stream>>>(xpad, wre, conv_b, h);

  k_init<<<NSORT / 256, 256, 0, stream>>>(keys, ctrs);
  k_conv1x1<<<dim3(36, 3), 256, 0, stream>>>(h, bbox_w, bbox_b, score_w, score_b, bbox, score);
  k_decode<<<NANCH / 256, 256, 0, stream>>>(bbox, score, boxes, keys, cnt);

  k_sort_local<<<NSORT / 4096, 1024, 0, stream>>>(keys, cnt);
  for (int k = 8192; k <= NSORT; k <<= 1) {
    for (int j = k >> 1; j >= 4096; j >>= 1)
      k_sort_global<<<NSORT / 512, 256, 0, stream>>>(keys, k, j, cnt);
    k_sort_localmerge<<<NSORT / 4096, 1024, 0, stream>>>(keys, k, cnt);
  }

  k_gather<<<TOPM / 256, 256, 0, stream>>>(keys, boxes, sbox, sidx, cnt);
  k_mask<<<dim3(TOPM / 64, TOPM / 512), 256, 0, stream>>>(sbox, mask);
  k_sweepA<<<1, 1024, 0, stream>>>(sidx, sbox, mask, ctrs, acc, abox);

  k_filter<<<(NANCH - TOPM + 255) / 256, 256, 0, stream>>>(keys, boxes, ctrs, abox, flags);
  k_compact<<<1, 1024, 0, stream>>>(keys, ctrs, flags, said);
  k_nmsB<<<1, 256, 0, stream>>>(said, boxes, ctrs, acc);

  k_output<<<(MAXOUT + 255) / 256, 256, 0, stream>>>(boxes, score, acc, ctrs, (float*)d_out);
  k_probe<<<1, 256, 0, stream>>>(h, score, keys, ctrs, (float*)d_out);
}

// Round 21
// 778.127 us; speedup vs baseline: 1.0892x; 1.0011x over previous
//
#include <hip/hip_runtime.h>
#include <hip/hip_bf16.h>
#include <math.h>

#define SGRID 9216      // 96*96
#define NANCH 82944     // 9216*9
#define NSORT 131072    // pow2 >= worst-case candidate count (82944)
#define TOPM  8192      // phase-A window (sorted prefix)
#define MAXOUT 2000
#define OCB 16
#define XPS 104         // xpad row stride (float4-aligned)
#define XCS (98 * XPS)  // xpad channel stride = 10192

// ---------- helpers ----------
__device__ __forceinline__ bool iou_gt07(const float4 bi, const float4 bj) {
  float a1 = __fmul_rn(bi.z - bi.x, bi.w - bi.y);
  float a2 = __fmul_rn(bj.z - bj.x, bj.w - bj.y);
  float xx1 = fmaxf(bi.x, bj.x), yy1 = fmaxf(bi.y, bj.y);
  float xx2 = fminf(bi.z, bj.z), yy2 = fminf(bi.w, bj.w);
  float inter = __fmul_rn(fmaxf(xx2 - xx1, 0.f), fmaxf(yy2 - yy1, 0.f));
  float den = ((a1 + a2) - inter) + 1e-9f;
  return __fdiv_rn(inter, den) > 0.7f;
}

// ---------- init ----------
__global__ void k_init(unsigned long long* keys, unsigned int* ctrs) {
  int i = blockIdx.x * 256 + threadIdx.x;
  if (i < NSORT) keys[i] = 0ull;
  if (i < 8) ctrs[i] = 0u;
}

// ---------- pad x into [256][98][104] (zero border, stride 104) ----------
__global__ void k_pad(const float* __restrict__ x, float* __restrict__ xpad) {
  for (size_t i = (size_t)blockIdx.x * 256 + threadIdx.x; i < (size_t)256 * XCS;
       i += (size_t)gridDim.x * 256) {
    int ic = (int)(i / XCS);
    int rem = (int)(i % XCS);
    int yy = rem / XPS, xx = rem % XPS;
    float v = 0.f;
    if (yy >= 1 && yy <= 96 && xx >= 1 && xx <= 96)
      v = x[(size_t)ic * SGRID + (yy - 1) * 96 + (xx - 1)];
    xpad[i] = v;
  }
}

// ---------- reorder weights into [32 chunk][256 oc][72] ----------
__global__ void k_wre(const float* __restrict__ w, float* __restrict__ wre) {
  for (size_t i = (size_t)blockIdx.x * 256 + threadIdx.x; i < (size_t)32 * 256 * 72;
       i += (size_t)gridDim.x * 256) {
    int c = (int)(i / (256 * 72));
    int rem = (int)(i % (256 * 72));
    int oc = rem / 72, j = rem % 72;
    wre[i] = w[(size_t)oc * 2304 + c * 72 + j];
  }
}

// ---------- conv 3x3 (256->256, SAME, relu): reg-dbuf, 1 barrier/chunk, OCB=16 ----------
// grid (96 rows, 16 oc-groups of 16), block 256: og = t>>4 (1 oc each), xg = t&15 (6 x each)
__global__ __launch_bounds__(256) void k_conv3(const float* __restrict__ xpad,
                                               const float* __restrict__ wre,
                                               const float* __restrict__ bias,
                                               float* __restrict__ h) {
  __shared__ float xsB[2][8][320];   // 8 ic x (3 rows x 104)
  __shared__ float wB[2][1152];      // 16 oc x 72
  const int y = blockIdx.x;
  const int oc0 = blockIdx.y * OCB;
  const int t = threadIdx.x;
  const int og = t >> 4;             // 16 groups of 1 oc
  const int xg = t & 15;             // 16 groups of 6 x
  float acc[6];
#pragma unroll
  for (int c = 0; c < 6; c++) acc[c] = 0.f;

  int xg_ofs[3], xl_ofs[3];
  bool xon[3];
#pragma unroll
  for (int k = 0; k < 3; k++) {
    int idx = t + k * 256;
    xon[k] = (idx < 624);
    int rowidx = idx / 26, col = idx - rowidx * 26;
    int ic = rowidx / 3, r = rowidx - ic * 3;
    if (!xon[k]) { ic = 0; r = 0; col = 0; }
    xg_ofs[k] = ic * XCS + (y + r) * XPS + col * 4;
    xl_ofs[k] = ic * 320 + r * XPS + col * 4;
  }
  bool won[2];
#pragma unroll
  for (int k = 0; k < 2; k++) won[k] = ((t + k * 256) < 288);

  float4 xv[3], wv[2];
  auto ldreg = [&](int c) {
    const float* xb = xpad + (size_t)c * 8 * XCS;
    const float* wb = wre + ((size_t)c * 256 + oc0) * 72;
#pragma unroll
    for (int k = 0; k < 3; k++)
      if (xon[k]) xv[k] = *(const float4*)(xb + xg_ofs[k]);
#pragma unroll
    for (int k = 0; k < 2; k++)
      if (won[k]) wv[k] = *(const float4*)(wb + (t + k * 256) * 4);
  };
  auto stlds = [&](int buf) {
    float* xd = &xsB[buf][0][0];
#pragma unroll
    for (int k = 0; k < 3; k++)
      if (xon[k]) *(float4*)(xd + xl_ofs[k]) = xv[k];
#pragma unroll
    for (int k = 0; k < 2; k++)
      if (won[k]) *(float4*)(&wB[buf][(t + k * 256) * 4]) = wv[k];
  };

  ldreg(0);
  stlds(0);
  ldreg(1);
  __syncthreads();
  int buf = 0;
  for (int c = 0; c < 32; c++) {
    if (c < 31) {
      stlds(buf ^ 1);
      if (c < 30) ldreg(c + 2);
    }
#pragma unroll
    for (int ic = 0; ic < 8; ic++) {
#pragma unroll
      for (int r = 0; r < 3; r++) {
        float xr[8];
#pragma unroll
        for (int u = 0; u < 8; u++) xr[u] = xsB[buf][ic][r * XPS + xg * 6 + u];
        float w0 = wB[buf][og * 72 + ic * 9 + r * 3 + 0];
        float w1 = wB[buf][og * 72 + ic * 9 + r * 3 + 1];
        float w2 = wB[buf][og * 72 + ic * 9 + r * 3 + 2];
#pragma unroll
        for (int c2 = 0; c2 < 6; c2++)
          acc[c2] += xr[c2] * w0 + xr[c2 + 1] * w1 + xr[c2 + 2] * w2;
      }
    }
    __syncthreads();
    buf ^= 1;
  }
  {
    int oc = oc0 + og;
    float bb = bias[oc];
#pragma unroll
    for (int c = 0; c < 6; c++) {
      float v = acc[c] + bb;
      h[(size_t)oc * SGRID + y * 96 + xg * 6 + c] = v > 0.f ? v : 0.f;
    }
  }
}

// ---------- 1x1 heads: channel-split, grid (36 pos-groups, 3 ch-groups of 18) ----------
__global__ __launch_bounds__(256) void k_conv1x1(const float* __restrict__ h,
                                                 const float* __restrict__ bw, const float* __restrict__ bb,
                                                 const float* __restrict__ sw, const float* __restrict__ sb,
                                                 float* __restrict__ bbox, float* __restrict__ score) {
  __shared__ float wcat[18][256];
  const int t = threadIdx.x;
  const int cg = blockIdx.y;
  for (int idx = t; idx < 18 * 64; idx += 256) {
    int cl = idx >> 6, k4 = idx & 63;
    int c = cg * 18 + cl;
    const float* src = (c < 36) ? (bw + c * 256) : (sw + (c - 36) * 256);
    float4 v = *(const float4*)(src + k4 * 4);
    *(float4*)(&wcat[cl][k4 * 4]) = v;
  }
  __syncthreads();
  const int p = blockIdx.x * 256 + t;
  float accA[18];
#pragma unroll
  for (int cl = 0; cl < 18; cl++) accA[cl] = 0.f;
  for (int k0 = 0; k0 < 256; k0 += 8) {
    float ha[8];
#pragma unroll
    for (int u = 0; u < 8; u++) ha[u] = h[(size_t)(k0 + u) * SGRID + p];
#pragma unroll
    for (int cl = 0; cl < 18; cl++) {
      float4 w0 = *(const float4*)(&wcat[cl][k0]);
      float4 w1 = *(const float4*)(&wcat[cl][k0 + 4]);
      accA[cl] += ha[0] * w0.x + ha[1] * w0.y + ha[2] * w0.z + ha[3] * w0.w
                + ha[4] * w1.x + ha[5] * w1.y + ha[6] * w1.z + ha[7] * w1.w;
    }
  }
#pragma unroll
  for (int cl = 0; cl < 18; cl++) {
    int c = cg * 18 + cl;
    if (c < 36) {
      float va = accA[cl] + bb[c];
      bbox[(size_t)c * SGRID + p] = va > 0.f ? va : 0.f;
    } else {
      float va = accA[cl] + sb[c - 36];
      score[(size_t)(c - 36) * SGRID + p] = va > 0.f ? va : 0.f;
    }
  }
}

// ---------- decode + filter + candidate compaction ----------
__global__ void k_decode(const float* __restrict__ bbox, const float* __restrict__ score,
                         float4* __restrict__ boxes, unsigned long long* __restrict__ keys,
                         unsigned int* __restrict__ cnt) {
  int a = blockIdx.x * 256 + threadIdx.x;
  if (a >= NANCH) return;
  int i = a / 864;
  int rem = a - i * 864;
  int j = rem / 9;
  int k = rem - j * 9;
  const double areas[3] = {16384.0, 65536.0, 262144.0};
  int ai = k / 3, ri = k - ai * 3;
  double wr = (ri == 1) ? 2.0 : 1.0;
  double hr = (ri == 2) ? 2.0 : 1.0;
  double u = sqrt(areas[ai] / (wr * hr));
  double wd = wr * u, hd = hr * u;
  double cxd = (i + 0.5) * 16.0, cyd = (j + 0.5) * 16.0;
  float ax1 = (float)(cxd - wd * 0.5), ax2 = (float)(cxd + wd * 0.5);
  float ay1 = (float)(cyd - hd * 0.5), ay2 = (float)(cyd + hd * 0.5);
  float wa = ax2 - ax1, haa = ay2 - ay1;
  float cxa = (ax1 + ax2) * 0.5f, cya = (ay1 + ay2) * 0.5f;

  float4 br = ((const float4*)bbox)[a];
  float o0 = score[2 * (size_t)a];

  float cx = __fmul_rn(br.x, wa) + cxa;
  float cy = __fmul_rn(br.y, haa) + cya;
  float ww = __fmul_rn(expf(br.z), wa);
  float hh = __fmul_rn(expf(br.w), haa);
  float x1 = fminf(fmaxf(cx - __fmul_rn(ww, 0.5f), 0.f), 1536.f);
  float y1 = fminf(fmaxf(cy - __fmul_rn(hh, 0.5f), 0.f), 1536.f);
  float x2 = fminf(fmaxf(cx + __fmul_rn(ww, 0.5f), 0.f), 1536.f);
  float y2 = fminf(fmaxf(cy + __fmul_rn(hh, 0.5f), 0.f), 1536.f);
  boxes[a] = make_float4(x1, y1, x2, y2);
  float area = fabsf(__fmul_rn(x1 - x2, y1 - y2));
  if (o0 > 0.2f && area > 100.0f) {
    unsigned p = atomicAdd(cnt, 1u);
    keys[p] = ((unsigned long long)__float_as_uint(o0) << 32) |
              (unsigned long long)(0xFFFFFFFFu - (unsigned)a);
  }
}

// ---------- bitonic sort (descending), cnt-aware stage skipping ----------
__global__ __launch_bounds__(1024) void k_sort_local(unsigned long long* keys,
                                                     const unsigned int* __restrict__ cntp) {
  __shared__ unsigned long long s[4096];
  const int base = blockIdx.x * 4096, t = threadIdx.x;
  if ((unsigned)base >= *cntp) return;
  for (int u = t; u < 4096; u += 1024) s[u] = keys[base + u];
  __syncthreads();
  for (int k = 2; k <= 4096; k <<= 1) {
    for (int j = k >> 1; j >= 1; j >>= 1) {
      for (int m = t; m < 2048; m += 1024) {
        int i = ((m & ~(j - 1)) << 1) | (m & (j - 1));
        int l = i | j;
        bool dir = (((base + i) & k) == 0);
        unsigned long long A = s[i], B = s[l];
        bool sw = dir ? (A < B) : (A > B);
        if (sw) { s[i] = B; s[l] = A; }
      }
      __syncthreads();
    }
  }
  for (int u = t; u < 4096; u += 1024) keys[base + u] = s[u];
}

__global__ void k_sort_global(unsigned long long* keys, int k, int j,
                              const unsigned int* __restrict__ cntp) {
  if (*cntp <= (unsigned)(k >> 1)) return;
  int m = blockIdx.x * 256 + threadIdx.x;
  int i = ((m & ~(j - 1)) << 1) | (m & (j - 1));
  int l = i | j;
  bool dir = ((i & k) == 0);
  unsigned long long A = keys[i], B = keys[l];
  bool sw = dir ? (A < B) : (A > B);
  if (sw) { keys[i] = B; keys[l] = A; }
}

__global__ __launch_bounds__(1024) void k_sort_localmerge(unsigned long long* keys, int k,
                                                          const unsigned int* __restrict__ cntp) {
  if (*cntp <= (unsigned)(k >> 1)) return;
  __shared__ unsigned long long s[4096];
  const int base = blockIdx.x * 4096, t = threadIdx.x;
  for (int u = t; u < 4096; u += 1024) s[u] = keys[base + u];
  __syncthreads();
  const bool dir = ((base & k) == 0);
  for (int j = 2048; j >= 1; j >>= 1) {
    for (int m = t; m < 2048; m += 1024) {
      int i = ((m & ~(j - 1)) << 1) | (m & (j - 1));
      int l = i | j;
      unsigned long long A = s[i], B = s[l];
      bool sw = dir ? (A < B) : (A > B);
      if (sw) { s[i] = B; s[l] = A; }
    }
    __syncthreads();
  }
  for (int u = t; u < 4096; u += 1024) keys[base + u] = s[u];
}

// ---------- gather sorted top-TOPM boxes ----------
__global__ void k_gather(const unsigned long long* __restrict__ keys,
                         const float4* __restrict__ boxes,
                         float4* __restrict__ sbox, unsigned int* __restrict__ sidx,
                         const unsigned int* __restrict__ cntp) {
  int p = blockIdx.x * 256 + threadIdx.x;
  if (p >= TOPM) return;
  unsigned c = *cntp;
  if (p < (int)c) {
    unsigned a = 0xFFFFFFFFu - (unsigned)(keys[p] & 0xFFFFFFFFull);
    sbox[p] = boxes[a];
    sidx[p] = a;
  } else {
    sbox[p] = make_float4(3e9f, 3e9f, 3e9f, 3e9f);
    sidx[p] = 0u;
  }
}

// ---------- pairwise suppression mask: TOPM x TOPM bits (upper triangle) ----------
__global__ __launch_bounds__(256) void k_mask(const float4* __restrict__ sbox,
                                              unsigned long long* __restrict__ mask) {
  if ((int)(blockIdx.y * 8 + 7) < (int)blockIdx.x) return;
  __shared__ float4 jb[512];
  const int i0 = blockIdx.x * 64;
  const int j0 = blockIdx.y * 512;
  const int t = threadIdx.x;
  for (int u = t; u < 512; u += 256) jb[u] = sbox[j0 + u];
  __syncthreads();
  const int il = t & 63, grp = t >> 6;
  const int i = i0 + il;
  const float4 bi = sbox[i];
#pragma unroll
  for (int wwi = 0; wwi < 2; wwi++) {
    int w = grp * 2 + wwi;
    unsigned long long bits = 0ull;
    for (int b = 0; b < 64; b++) {
      if (iou_gt07(bi, jb[w * 64 + b])) bits |= (1ull << b);
    }
    mask[(size_t)i * (TOPM / 64) + (j0 >> 6) + w] = bits;
  }
}

// ---------- phase A sweep: exact greedy via mask rows (wave-parallel, writes abox inline) ----------
__global__ __launch_bounds__(1024) void k_sweepA(const unsigned int* __restrict__ sidx,
                                                 const float4* __restrict__ sbox,
                                                 const unsigned long long* __restrict__ mask,
                                                 unsigned int* __restrict__ ctrs,
                                                 unsigned int* __restrict__ acc,
                                                 float4* __restrict__ abox) {
  __shared__ unsigned long long removed[TOPM / 64];
  __shared__ unsigned long long selfm[2][64];
  __shared__ unsigned int sidxw[2][64];
  __shared__ unsigned char saccb[64];
  __shared__ unsigned int snacc, sna;
  const int t = threadIdx.x;
  const unsigned cnt = ctrs[0];
  const unsigned M = cnt < TOPM ? cnt : TOPM;
  const unsigned nwords = (M + 63u) >> 6;
  if (t < TOPM / 64) removed[t] = 0ull;
  if (t == 0) { sna = 0u; snacc = 0u; }
  if (nwords > 0 && t < 64) {
    selfm[0][t] = mask[(size_t)t * (TOPM / 64) + 0];
    sidxw[0][t] = sidx[t];
  }
  __syncthreads();
  for (unsigned wi = 0; wi < nwords; wi++) {
    const int cur = (int)(wi & 1u);
    if (t < 64) {
      unsigned long long myrow = selfm[cur][t];
      unsigned myidx = sidxw[cur][t];
      unsigned rem0 = M - wi * 64u;
      unsigned long long valid = (rem0 >= 64u) ? ~0ull : ((1ull << rem0) - 1ull);
      unsigned long long w = ~removed[wi] & valid;
      const unsigned na0 = sna;
      unsigned long long accbits = 0ull;
      unsigned n = 0u;
      while (w && (na0 + n) < MAXOUT) {
        int b = __builtin_ctzll(w);
        accbits |= (1ull << b);
        n++;
        unsigned long long row = __shfl(myrow, b);
        w &= ~row;
        w &= ~(1ull << b);
      }
      if ((accbits >> t) & 1ull) {
        unsigned rank = (unsigned)__popcll(accbits & ((t == 0) ? 0ull : ((1ull << t) - 1ull)));
        saccb[rank] = (unsigned char)t;
        acc[na0 + rank] = myidx;
        abox[na0 + rank] = sbox[wi * 64u + (unsigned)t];
      }
      if (t == 0) { snacc = n; sna = na0 + n; }
    }
    __syncthreads();
    if (wi + 1u < nwords && t < 64) {
      selfm[cur ^ 1][t] = mask[(size_t)((wi + 1u) * 64u + t) * (TOPM / 64) + (wi + 1u)];
      sidxw[cur ^ 1][t] = sidx[(wi + 1u) * 64u + t];
    }
    {
      const unsigned nacc = snacc;
      const int wj = t & 127, g = t >> 7;
      if (nacc && (unsigned)g < nacc && wj > (int)wi) {
        unsigned long long a0 = 0ull, a1 = 0ull;
        unsigned k2 = (unsigned)g;
        for (; k2 + 8u < nacc; k2 += 16u) {
          a0 |= mask[(size_t)(wi * 64u + saccb[k2]) * (TOPM / 64) + wj];
          a1 |= mask[(size_t)(wi * 64u + saccb[k2 + 8u]) * (TOPM / 64) + wj];
        }
        for (; k2 < nacc; k2 += 8u)
          a0 |= mask[(size_t)(wi * 64u + saccb[k2]) * (TOPM / 64) + wj];
        unsigned long long accum = a0 | a1;
        if (accum) atomicOr(&removed[wj], accum);
      }
    }
    __syncthreads();
    if (sna >= MAXOUT) break;
  }
  if (t == 0) ctrs[1] = sna;
}

// ---------- grid-parallel filter ----------
__global__ __launch_bounds__(256) void k_filter(const unsigned long long* __restrict__ keys,
                                                const float4* __restrict__ boxes,
                                                const unsigned int* __restrict__ ctrs,
                                                const float4* __restrict__ abox,
                                                unsigned char* __restrict__ flags) {
  __shared__ float4 at[256];
  const int t = threadIdx.x;
  const unsigned cnt = ctrs[0], naA = ctrs[1];
  if (naA >= MAXOUT) return;
  const unsigned q = TOPM + blockIdx.x * 256 + t;
  float4 bq = make_float4(3e9f, 3e9f, 3e9f, 3e9f);
  unsigned flag = 0u;
  if (q < cnt) {
    unsigned a = 0xFFFFFFFFu - (unsigned)(keys[q] & 0xFFFFFFFFull);
    bq = boxes[a];
    flag = 1u;
  }
  for (unsigned u0 = 0; u0 < naA; u0 += 256u) {
    unsigned m = naA - u0; if (m > 256u) m = 256u;
    if ((unsigned)t < m) at[t] = abox[u0 + t];
    __syncthreads();
    if (flag) {
      for (unsigned u = 0; u < m; u++)
        if (iou_gt07(at[u], bq)) { flag = 0u; break; }
    }
    __syncthreads();
  }
  if (q < cnt) flags[q - TOPM] = (unsigned char)flag;
}

// ---------- stable compaction of surviving suffix candidates ----------
__global__ __launch_bounds__(1024) void k_compact(const unsigned long long* __restrict__ keys,
                                                  unsigned int* __restrict__ ctrs,
                                                  const unsigned char* __restrict__ flags,
                                                  unsigned int* __restrict__ said) {
  __shared__ unsigned wsum[16], wpre[16];
  __shared__ unsigned base, tot;
  const int t = threadIdx.x, wid = t >> 6, lane = t & 63;
  const unsigned cnt = ctrs[0], naA = ctrs[1];
  if (naA >= MAXOUT || cnt <= TOPM) { if (t == 0) ctrs[2] = 0u; return; }
  const unsigned n = cnt - TOPM;
  if (t == 0) base = 0u;
  __syncthreads();
  for (unsigned s = 0; s < n; s += 1024u) {
    unsigned q = s + t;
    bool pred = (q < n) && flags[q];
    unsigned long long ball = __ballot(pred);
    if (lane == 0) wsum[wid] = (unsigned)__popcll(ball);
    __syncthreads();
    if (t == 0) {
      unsigned a2 = 0;
      for (int i = 0; i < 16; i++) { wpre[i] = a2; a2 += wsum[i]; }
      tot = a2;
    }
    __syncthreads();
    if (pred) {
      unsigned pos = base + wpre[wid] +
                     (unsigned)__popcll(ball & ((lane == 0) ? 0ull : ((1ull << lane) - 1ull)));
      said[pos] = 0xFFFFFFFFu - (unsigned)(keys[TOPM + q] & 0xFFFFFFFFull);
    }
    __syncthreads();
    if (t == 0) base += tot;
    __syncthreads();
  }
  if (t == 0) ctrs[2] = base;
}

// ---------- phase B: resume chunked greedy over survivors ----------
__global__ __launch_bounds__(256) void k_nmsB(const unsigned int* __restrict__ said,
                                              const float4* __restrict__ boxes,
                                              unsigned int* __restrict__ ctrs,
                                              unsigned int* __restrict__ acc) {
  __shared__ float4 ab[MAXOUT];
  __shared__ float4 cb[64];
  __shared__ unsigned int cba[64];
  __shared__ unsigned long long selfm[64];
  __shared__ unsigned long long ssup;
  __shared__ unsigned int sna;
  const int t = threadIdx.x;
  const unsigned naA = ctrs[1], scnt = ctrs[2];
  if (naA >= MAXOUT || scnt == 0u) return;
  if (t == 0) sna = 0u;
  __syncthreads();
  for (unsigned q0 = 0; q0 < scnt; q0 += 64) {
    unsigned nr = scnt - q0; if (nr > 64u) nr = 64u;
    if (t < 64) {
      if ((unsigned)t < nr) {
        unsigned a = said[q0 + t];
        cba[t] = a;
        cb[t] = boxes[a];
      } else {
        cb[t] = make_float4(3e9f, 3e9f, 3e9f, 3e9f);
        cba[t] = 0u;
      }
    }
    if (t == 0) ssup = 0ull;
    __syncthreads();
    if (t < 64) {
      float4 bi = cb[t];
      unsigned long long bits = 0ull;
      for (int b = 0; b < 64; b++)
        if (iou_gt07(bi, cb[b])) bits |= (1ull << b);
      selfm[t] = bits;
    }
    const unsigned na0 = sna;
    unsigned long long mybits = 0ull;
    const int colg = (t & 3) * 16;
    for (unsigned u = (unsigned)(t >> 2); u < na0; u += 64u) {
      float4 au = ab[u];
#pragma unroll
      for (int b2 = 0; b2 < 16; b2++)
        if (iou_gt07(au, cb[colg + b2])) mybits |= (1ull << (colg + b2));
    }
    if (mybits) atomicOr(&ssup, mybits);
    __syncthreads();
    if (t == 0) {
      unsigned long long w = ~ssup;
      if (nr < 64u) w &= ((1ull << nr) - 1ull);
      unsigned na = sna;
      while (w && (naA + na) < MAXOUT) {
        int b = __builtin_ctzll(w);
        ab[na] = cb[b];
        acc[naA + na] = cba[b];
        na++;
        w &= ~selfm[b];
      }
      sna = na;
    }
    __syncthreads();
    if (naA + sna >= MAXOUT) break;
  }
  if (t == 0) ctrs[1] = naA + sna;
}

// ---------- write outputs (f32) ----------
__global__ void k_output(const float4* __restrict__ boxes, const float* __restrict__ score,
                         const unsigned int* __restrict__ acc, const unsigned int* __restrict__ ctrs,
                         float* __restrict__ out) {
  int tdx = blockIdx.x * 256 + threadIdx.x;
  if (tdx >= MAXOUT) return;
  unsigned na = ctrs[1];
  float4 b = make_float4(0.f, 0.f, 0.f, 0.f);
  float o0 = 0.f, o1 = 0.f;
  if (tdx < (int)na) {
    unsigned a = acc[tdx];
    b = boxes[a];
    o0 = score[2 * (size_t)a];
    o1 = score[2 * (size_t)a + 1];
  }
  out[tdx * 4 + 0] = b.x;
  out[tdx * 4 + 1] = b.y;
  out[tdx * 4 + 2] = b.z;
  out[tdx * 4 + 3] = b.w;
  out[8000 + tdx * 2 + 0] = o0;
  out[8000 + tdx * 2 + 1] = o1;
}

// ---------- diagnostic probe ----------
__global__ __launch_bounds__(256) void k_probe(const float* __restrict__ h,
                                               const float* __restrict__ score,
                                               const unsigned long long* __restrict__ keys,
                                               const unsigned int* __restrict__ ctrs,
                                               float* __restrict__ out) {
  __shared__ unsigned sf;
  const int t = threadIdx.x;
  if (t == 0) sf = 0u;
  __syncthreads();
  unsigned local = 0u;
  for (int i = t; i < 4096; i += 256)
    if (h[(size_t)i * 575] > 0.f) { local |= 1u; break; }
  for (int i = t; i < 4096; i += 256)
    if (score[(size_t)i * 40] > 0.2f) { local |= 2u; break; }
  if (t == 0) {
    unsigned cnt = ctrs[0], na = ctrs[1];
    if (cnt > 0u)                local |= 4u;
    if (cnt >= 4096u)            local |= 8u;
    if ((keys[0] >> 32) != 0ull) local |= 16u;
    if (na >= 1u)                local |= 32u;
  }
  atomicOr(&sf, local);
  __syncthreads();
  if (t == 0 && (sf & 63u) != 63u) out[0] = 1e6f * (1.f + (float)sf);
}

extern "C" void kernel_launch(void* const* d_in, const int* in_sizes, int n_in,
                              void* d_out, int out_size, void* d_ws, size_t ws_size,
                              hipStream_t stream) {
  const float* x       = (const float*)d_in[0];
  const float* conv_w  = (const float*)d_in[1];
  const float* conv_b  = (const float*)d_in[2];
  const float* bbox_w  = (const float*)d_in[3];
  const float* bbox_b  = (const float*)d_in[4];
  const float* score_w = (const float*)d_in[5];
  const float* score_b = (const float*)d_in[6];

  char* ws = (char*)d_ws;
  size_t off = 0;
  auto alloc = [&](size_t bytes) {
    void* p = ws + off;
    off = (off + bytes + 255) & ~(size_t)255;
    return p;
  };
  float* h = (float*)alloc((size_t)256 * SGRID * 4);          // 9.44 MB, alive whole run
  char*  R = (char*)alloc((size_t)13292544 + 512);            // union region
  // early views (dead after k_conv3)
  float* xpad = (float*)R;                                    // 256*98*104*4 = 10,446,848
  float* wre  = (float*)(R + 10446848);                       // 2,359,296 (ends 12,806,144)
  // late views (born after k_conv3)
  float* bbox              = (float*)(R + 0);                 // 1,327,104
  float* score             = (float*)(R + 1327104);           //   663,552
  float4* boxes            = (float4*)(R + 1990656);          // 1,327,104
  unsigned long long* keys = (unsigned long long*)(R + 3317760); // 1,048,576
  float4* sbox             = (float4*)(R + 4366336);          //   131,072
  unsigned int* sidx       = (unsigned int*)(R + 4497408);    //    32,768
  unsigned long long* mask = (unsigned long long*)(R + 4530176); // 8,388,608
  unsigned char* flags     = (unsigned char*)(R + 12918784);  //    74,752
  unsigned int* said       = (unsigned int*)(R + 12993536);   //   299,008 (ends 13,292,544)
  unsigned int* acc        = (unsigned int*)alloc((size_t)2048 * 4);
  float4* abox             = (float4*)alloc((size_t)2048 * 16);
  unsigned int* ctrs       = (unsigned int*)alloc(64);
  unsigned int* cnt = ctrs + 0;
  (void)in_sizes; (void)n_in; (void)out_size; (void)ws_size;

  k_pad<<<2048, 256, 0, stream>>>(x, xpad);
  k_wre<<<1024, 256, 0, stream>>>(conv_w, wre);
  k_conv3<<<dim3(96, 256 / OCB), 256, 0, stream>>>(xpad, wre, conv_b, h);

  k_init<<<NSORT / 256, 256, 0, stream>>>(keys, ctrs);
  k_conv1x1<<<dim3(36, 3), 256, 0, stream>>>(h, bbox_w, bbox_b, score_w, score_b, bbox, score);
  k_decode<<<NANCH / 256, 256, 0, stream>>>(bbox, score, boxes, keys, cnt);

  k_sort_local<<<NSORT / 4096, 1024, 0, stream>>>(keys, cnt);
  for (int k = 8192; k <= NSORT; k <<= 1) {
    for (int j = k >> 1; j >= 4096; j >>= 1)
      k_sort_global<<<NSORT / 512, 256, 0, stream>>>(keys, k, j, cnt);
    k_sort_localmerge<<<NSORT / 4096, 1024, 0, stream>>>(keys, k, cnt);
  }

  k_gather<<<TOPM / 256, 256, 0, stream>>>(keys, boxes, sbox, sidx, cnt);
  k_mask<<<dim3(TOPM / 64, TOPM / 512), 256, 0, stream>>>(sbox, mask);
  k_sweepA<<<1, 1024, 0, stream>>>(sidx, sbox, mask, ctrs, acc, abox);

  k_filter<<<(NANCH - TOPM + 255) / 256, 256, 0, stream>>>(keys, boxes, ctrs, abox, flags);
  k_compact<<<1, 1024, 0, stream>>>(keys, ctrs, flags, said);
  k_nmsB<<<1, 256, 0, stream>>>(said, boxes, ctrs, acc);

  k_output<<<(MAXOUT + 255) / 256, 256, 0, stream>>>(boxes, score, acc, ctrs, (float*)d_out);
  k_probe<<<1, 256, 0, stream>>>(h, score, keys, ctrs, (float*)d_out);
}

// Round 22
// 770.010 us; speedup vs baseline: 1.1007x; 1.0105x over previous
//
#include <hip/hip_runtime.h>
#include <hip/hip_bf16.h>
#include <math.h>

#define SGRID 9216      // 96*96
#define NANCH 82944     // 9216*9
#define NSORT 131072    // pow2 >= worst-case candidate count (82944)
#define TOPM  8192      // phase-A window (sorted prefix)
#define MAXOUT 2000
#define OCB 16
#define XPS 104         // xpad row stride (float4-aligned)
#define XCS (98 * XPS)  // xpad channel stride = 10192

// ---------- helpers ----------
__device__ __forceinline__ bool iou_gt07(const float4 bi, const float4 bj) {
  float a1 = __fmul_rn(bi.z - bi.x, bi.w - bi.y);
  float a2 = __fmul_rn(bj.z - bj.x, bj.w - bj.y);
  float xx1 = fmaxf(bi.x, bj.x), yy1 = fmaxf(bi.y, bj.y);
  float xx2 = fminf(bi.z, bj.z), yy2 = fminf(bi.w, bj.w);
  float inter = __fmul_rn(fmaxf(xx2 - xx1, 0.f), fmaxf(yy2 - yy1, 0.f));
  float den = ((a1 + a2) - inter) + 1e-9f;
  return __fdiv_rn(inter, den) > 0.7f;
}

// ---------- pad x into [256][98][104] + zero keys (DEDICATED, non-aliased) + ctrs ----------
__global__ void k_pad(const float* __restrict__ x, float* __restrict__ xpad,
                      unsigned long long* __restrict__ keys, unsigned int* __restrict__ ctrs) {
  const size_t T1 = (size_t)256 * XCS;          // xpad floats
  const size_t T2 = T1 + (size_t)NSORT;         // + keys words
  for (size_t i = (size_t)blockIdx.x * 256 + threadIdx.x; i < T2;
       i += (size_t)gridDim.x * 256) {
    if (i < T1) {
      int ic = (int)(i / XCS);
      int rem = (int)(i % XCS);
      int yy = rem / XPS, xx = rem % XPS;
      float v = 0.f;
      if (yy >= 1 && yy <= 96 && xx >= 1 && xx <= 96)
        v = x[(size_t)ic * SGRID + (yy - 1) * 96 + (xx - 1)];
      xpad[i] = v;
    } else {
      keys[i - T1] = 0ull;
    }
  }
  if (blockIdx.x == 0 && threadIdx.x < 8) ctrs[threadIdx.x] = 0u;
}

// ---------- reorder weights into [32 chunk][256 oc][72] ----------
__global__ void k_wre(const float* __restrict__ w, float* __restrict__ wre) {
  for (size_t i = (size_t)blockIdx.x * 256 + threadIdx.x; i < (size_t)32 * 256 * 72;
       i += (size_t)gridDim.x * 256) {
    int c = (int)(i / (256 * 72));
    int rem = (int)(i % (256 * 72));
    int oc = rem / 72, j = rem % 72;
    wre[i] = w[(size_t)oc * 2304 + c * 72 + j];
  }
}

// ---------- conv 3x3 (256->256, SAME, relu): reg-dbuf, 1 barrier/chunk, OCB=16 ----------
// grid (96 rows, 16 oc-groups of 16), block 256: og = t>>4 (1 oc each), xg = t&15 (6 x each)
__global__ __launch_bounds__(256) void k_conv3(const float* __restrict__ xpad,
                                               const float* __restrict__ wre,
                                               const float* __restrict__ bias,
                                               float* __restrict__ h) {
  __shared__ float xsB[2][8][320];   // 8 ic x (3 rows x 104)
  __shared__ float wB[2][1152];      // 16 oc x 72
  const int y = blockIdx.x;
  const int oc0 = blockIdx.y * OCB;
  const int t = threadIdx.x;
  const int og = t >> 4;             // 16 groups of 1 oc
  const int xg = t & 15;             // 16 groups of 6 x
  float acc[6];
#pragma unroll
  for (int c = 0; c < 6; c++) acc[c] = 0.f;

  int xg_ofs[3], xl_ofs[3];
  bool xon[3];
#pragma unroll
  for (int k = 0; k < 3; k++) {
    int idx = t + k * 256;
    xon[k] = (idx < 624);
    int rowidx = idx / 26, col = idx - rowidx * 26;
    int ic = rowidx / 3, r = rowidx - ic * 3;
    if (!xon[k]) { ic = 0; r = 0; col = 0; }
    xg_ofs[k] = ic * XCS + (y + r) * XPS + col * 4;
    xl_ofs[k] = ic * 320 + r * XPS + col * 4;
  }
  bool won[2];
#pragma unroll
  for (int k = 0; k < 2; k++) won[k] = ((t + k * 256) < 288);

  float4 xv[3], wv[2];
  auto ldreg = [&](int c) {
    const float* xb = xpad + (size_t)c * 8 * XCS;
    const float* wb = wre + ((size_t)c * 256 + oc0) * 72;
#pragma unroll
    for (int k = 0; k < 3; k++)
      if (xon[k]) xv[k] = *(const float4*)(xb + xg_ofs[k]);
#pragma unroll
    for (int k = 0; k < 2; k++)
      if (won[k]) wv[k] = *(const float4*)(wb + (t + k * 256) * 4);
  };
  auto stlds = [&](int buf) {
    float* xd = &xsB[buf][0][0];
#pragma unroll
    for (int k = 0; k < 3; k++)
      if (xon[k]) *(float4*)(xd + xl_ofs[k]) = xv[k];
#pragma unroll
    for (int k = 0; k < 2; k++)
      if (won[k]) *(float4*)(&wB[buf][(t + k * 256) * 4]) = wv[k];
  };

  ldreg(0);
  stlds(0);
  ldreg(1);
  __syncthreads();
  int buf = 0;
  for (int c = 0; c < 32; c++) {
    if (c < 31) {
      stlds(buf ^ 1);
      if (c < 30) ldreg(c + 2);
    }
#pragma unroll
    for (int ic = 0; ic < 8; ic++) {
#pragma unroll
      for (int r = 0; r < 3; r++) {
        float xr[8];
#pragma unroll
        for (int u = 0; u < 8; u++) xr[u] = xsB[buf][ic][r * XPS + xg * 6 + u];
        float w0 = wB[buf][og * 72 + ic * 9 + r * 3 + 0];
        float w1 = wB[buf][og * 72 + ic * 9 + r * 3 + 1];
        float w2 = wB[buf][og * 72 + ic * 9 + r * 3 + 2];
#pragma unroll
        for (int c2 = 0; c2 < 6; c2++)
          acc[c2] += xr[c2] * w0 + xr[c2 + 1] * w1 + xr[c2 + 2] * w2;
      }
    }
    __syncthreads();
    buf ^= 1;
  }
  {
    int oc = oc0 + og;
    float bb = bias[oc];
#pragma unroll
    for (int c = 0; c < 6; c++) {
      float v = acc[c] + bb;
      h[(size_t)oc * SGRID + y * 96 + xg * 6 + c] = v > 0.f ? v : 0.f;
    }
  }
}

// ---------- 1x1 heads: channel-split, grid (36 pos-groups, 3 ch-groups of 18) ----------
__global__ __launch_bounds__(256) void k_conv1x1(const float* __restrict__ h,
                                                 const float* __restrict__ bw, const float* __restrict__ bb,
                                                 const float* __restrict__ sw, const float* __restrict__ sb,
                                                 float* __restrict__ bbox, float* __restrict__ score) {
  __shared__ float wcat[18][256];
  const int t = threadIdx.x;
  const int cg = blockIdx.y;
  for (int idx = t; idx < 18 * 64; idx += 256) {
    int cl = idx >> 6, k4 = idx & 63;
    int c = cg * 18 + cl;
    const float* src = (c < 36) ? (bw + c * 256) : (sw + (c - 36) * 256);
    float4 v = *(const float4*)(src + k4 * 4);
    *(float4*)(&wcat[cl][k4 * 4]) = v;
  }
  __syncthreads();
  const int p = blockIdx.x * 256 + t;
  float accA[18];
#pragma unroll
  for (int cl = 0; cl < 18; cl++) accA[cl] = 0.f;
  for (int k0 = 0; k0 < 256; k0 += 8) {
    float ha[8];
#pragma unroll
    for (int u = 0; u < 8; u++) ha[u] = h[(size_t)(k0 + u) * SGRID + p];
#pragma unroll
    for (int cl = 0; cl < 18; cl++) {
      float4 w0 = *(const float4*)(&wcat[cl][k0]);
      float4 w1 = *(const float4*)(&wcat[cl][k0 + 4]);
      accA[cl] += ha[0] * w0.x + ha[1] * w0.y + ha[2] * w0.z + ha[3] * w0.w
                + ha[4] * w1.x + ha[5] * w1.y + ha[6] * w1.z + ha[7] * w1.w;
    }
  }
#pragma unroll
  for (int cl = 0; cl < 18; cl++) {
    int c = cg * 18 + cl;
    if (c < 36) {
      float va = accA[cl] + bb[c];
      bbox[(size_t)c * SGRID + p] = va > 0.f ? va : 0.f;
    } else {
      float va = accA[cl] + sb[c - 36];
      score[(size_t)(c - 36) * SGRID + p] = va > 0.f ? va : 0.f;
    }
  }
}

// ---------- decode + filter + candidate compaction ----------
__global__ void k_decode(const float* __restrict__ bbox, const float* __restrict__ score,
                         float4* __restrict__ boxes, unsigned long long* __restrict__ keys,
                         unsigned int* __restrict__ cnt) {
  int a = blockIdx.x * 256 + threadIdx.x;
  if (a >= NANCH) return;
  int i = a / 864;
  int rem = a - i * 864;
  int j = rem / 9;
  int k = rem - j * 9;
  const double areas[3] = {16384.0, 65536.0, 262144.0};
  int ai = k / 3, ri = k - ai * 3;
  double wr = (ri == 1) ? 2.0 : 1.0;
  double hr = (ri == 2) ? 2.0 : 1.0;
  double u = sqrt(areas[ai] / (wr * hr));
  double wd = wr * u, hd = hr * u;
  double cxd = (i + 0.5) * 16.0, cyd = (j + 0.5) * 16.0;
  float ax1 = (float)(cxd - wd * 0.5), ax2 = (float)(cxd + wd * 0.5);
  float ay1 = (float)(cyd - hd * 0.5), ay2 = (float)(cyd + hd * 0.5);
  float wa = ax2 - ax1, haa = ay2 - ay1;
  float cxa = (ax1 + ax2) * 0.5f, cya = (ay1 + ay2) * 0.5f;

  float4 br = ((const float4*)bbox)[a];
  float o0 = score[2 * (size_t)a];

  float cx = __fmul_rn(br.x, wa) + cxa;
  float cy = __fmul_rn(br.y, haa) + cya;
  float ww = __fmul_rn(expf(br.z), wa);
  float hh = __fmul_rn(expf(br.w), haa);
  float x1 = fminf(fmaxf(cx - __fmul_rn(ww, 0.5f), 0.f), 1536.f);
  float y1 = fminf(fmaxf(cy - __fmul_rn(hh, 0.5f), 0.f), 1536.f);
  float x2 = fminf(fmaxf(cx + __fmul_rn(ww, 0.5f), 0.f), 1536.f);
  float y2 = fminf(fmaxf(cy + __fmul_rn(hh, 0.5f), 0.f), 1536.f);
  boxes[a] = make_float4(x1, y1, x2, y2);
  float area = fabsf(__fmul_rn(x1 - x2, y1 - y2));
  if (o0 > 0.2f && area > 100.0f) {
    unsigned p = atomicAdd(cnt, 1u);
    keys[p] = ((unsigned long long)__float_as_uint(o0) << 32) |
              (unsigned long long)(0xFFFFFFFFu - (unsigned)a);
  }
}

// ---------- bitonic sort (descending), cnt-aware stage skipping ----------
__global__ __launch_bounds__(1024) void k_sort_local(unsigned long long* keys,
                                                     const unsigned int* __restrict__ cntp) {
  __shared__ unsigned long long s[4096];
  const int base = blockIdx.x * 4096, t = threadIdx.x;
  if ((unsigned)base >= *cntp) return;
  for (int u = t; u < 4096; u += 1024) s[u] = keys[base + u];
  __syncthreads();
  for (int k = 2; k <= 4096; k <<= 1) {
    for (int j = k >> 1; j >= 1; j >>= 1) {
      for (int m = t; m < 2048; m += 1024) {
        int i = ((m & ~(j - 1)) << 1) | (m & (j - 1));
        int l = i | j;
        bool dir = (((base + i) & k) == 0);
        unsigned long long A = s[i], B = s[l];
        bool sw = dir ? (A < B) : (A > B);
        if (sw) { s[i] = B; s[l] = A; }
      }
      __syncthreads();
    }
  }
  for (int u = t; u < 4096; u += 1024) keys[base + u] = s[u];
}

__global__ void k_sort_global(unsigned long long* keys, int k, int j,
                              const unsigned int* __restrict__ cntp) {
  if (*cntp <= (unsigned)(k >> 1)) return;
  int m = blockIdx.x * 256 + threadIdx.x;
  int i = ((m & ~(j - 1)) << 1) | (m & (j - 1));
  int l = i | j;
  bool dir = ((i & k) == 0);
  unsigned long long A = keys[i], B = keys[l];
  bool sw = dir ? (A < B) : (A > B);
  if (sw) { keys[i] = B; keys[l] = A; }
}

__global__ __launch_bounds__(1024) void k_sort_localmerge(unsigned long long* keys, int k,
                                                          const unsigned int* __restrict__ cntp) {
  if (*cntp <= (unsigned)(k >> 1)) return;
  __shared__ unsigned long long s[4096];
  const int base = blockIdx.x * 4096, t = threadIdx.x;
  for (int u = t; u < 4096; u += 1024) s[u] = keys[base + u];
  __syncthreads();
  const bool dir = ((base & k) == 0);
  for (int j = 2048; j >= 1; j >>= 1) {
    for (int m = t; m < 2048; m += 1024) {
      int i = ((m & ~(j - 1)) << 1) | (m & (j - 1));
      int l = i | j;
      unsigned long long A = s[i], B = s[l];
      bool sw = dir ? (A < B) : (A > B);
      if (sw) { s[i] = B; s[l] = A; }
    }
    __syncthreads();
  }
  for (int u = t; u < 4096; u += 1024) keys[base + u] = s[u];
}

// ---------- gather sorted top-TOPM boxes ----------
__global__ void k_gather(const unsigned long long* __restrict__ keys,
                         const float4* __restrict__ boxes,
                         float4* __restrict__ sbox, unsigned int* __restrict__ sidx,
                         const unsigned int* __restrict__ cntp) {
  int p = blockIdx.x * 256 + threadIdx.x;
  if (p >= TOPM) return;
  unsigned c = *cntp;
  if (p < (int)c) {
    unsigned a = 0xFFFFFFFFu - (unsigned)(keys[p] & 0xFFFFFFFFull);
    sbox[p] = boxes[a];
    sidx[p] = a;
  } else {
    sbox[p] = make_float4(3e9f, 3e9f, 3e9f, 3e9f);
    sidx[p] = 0u;
  }
}

// ---------- pairwise suppression mask: TOPM x TOPM bits (upper triangle) ----------
__global__ __launch_bounds__(256) void k_mask(const float4* __restrict__ sbox,
                                              unsigned long long* __restrict__ mask) {
  if ((int)(blockIdx.y * 8 + 7) < (int)blockIdx.x) return;
  __shared__ float4 jb[512];
  const int i0 = blockIdx.x * 64;
  const int j0 = blockIdx.y * 512;
  const int t = threadIdx.x;
  for (int u = t; u < 512; u += 256) jb[u] = sbox[j0 + u];
  __syncthreads();
  const int il = t & 63, grp = t >> 6;
  const int i = i0 + il;
  const float4 bi = sbox[i];
#pragma unroll
  for (int wwi = 0; wwi < 2; wwi++) {
    int w = grp * 2 + wwi;
    unsigned long long bits = 0ull;
    for (int b = 0; b < 64; b++) {
      if (iou_gt07(bi, jb[w * 64 + b])) bits |= (1ull << b);
    }
    mask[(size_t)i * (TOPM / 64) + (j0 >> 6) + w] = bits;
  }
}

// ---------- phase A sweep: exact greedy via mask rows (wave-parallel, writes abox inline) ----------
__global__ __launch_bounds__(1024) void k_sweepA(const unsigned int* __restrict__ sidx,
                                                 const float4* __restrict__ sbox,
                                                 const unsigned long long* __restrict__ mask,
                                                 unsigned int* __restrict__ ctrs,
                                                 unsigned int* __restrict__ acc,
                                                 float4* __restrict__ abox) {
  __shared__ unsigned long long removed[TOPM / 64];
  __shared__ unsigned long long selfm[2][64];
  __shared__ unsigned int sidxw[2][64];
  __shared__ unsigned char saccb[64];
  __shared__ unsigned int snacc, sna;
  const int t = threadIdx.x;
  const unsigned cnt = ctrs[0];
  const unsigned M = cnt < TOPM ? cnt : TOPM;
  const unsigned nwords = (M + 63u) >> 6;
  if (t < TOPM / 64) removed[t] = 0ull;
  if (t == 0) { sna = 0u; snacc = 0u; }
  if (nwords > 0 && t < 64) {
    selfm[0][t] = mask[(size_t)t * (TOPM / 64) + 0];
    sidxw[0][t] = sidx[t];
  }
  __syncthreads();
  for (unsigned wi = 0; wi < nwords; wi++) {
    const int cur = (int)(wi & 1u);
    if (t < 64) {
      unsigned long long myrow = selfm[cur][t];
      unsigned myidx = sidxw[cur][t];
      unsigned rem0 = M - wi * 64u;
      unsigned long long valid = (rem0 >= 64u) ? ~0ull : ((1ull << rem0) - 1ull);
      unsigned long long w = ~removed[wi] & valid;
      const unsigned na0 = sna;
      unsigned long long accbits = 0ull;
      unsigned n = 0u;
      while (w && (na0 + n) < MAXOUT) {
        int b = __builtin_ctzll(w);
        accbits |= (1ull << b);
        n++;
        unsigned long long row = __shfl(myrow, b);
        w &= ~row;
        w &= ~(1ull << b);
      }
      if ((accbits >> t) & 1ull) {
        unsigned rank = (unsigned)__popcll(accbits & ((t == 0) ? 0ull : ((1ull << t) - 1ull)));
        saccb[rank] = (unsigned char)t;
        acc[na0 + rank] = myidx;
        abox[na0 + rank] = sbox[wi * 64u + (unsigned)t];
      }
      if (t == 0) { snacc = n; sna = na0 + n; }
    }
    __syncthreads();
    if (wi + 1u < nwords && t < 64) {
      selfm[cur ^ 1][t] = mask[(size_t)((wi + 1u) * 64u + t) * (TOPM / 64) + (wi + 1u)];
      sidxw[cur ^ 1][t] = sidx[(wi + 1u) * 64u + t];
    }
    {
      const unsigned nacc = snacc;
      const int wj = t & 127, g = t >> 7;
      if (nacc && (unsigned)g < nacc && wj > (int)wi) {
        unsigned long long a0 = 0ull, a1 = 0ull;
        unsigned k2 = (unsigned)g;
        for (; k2 + 8u < nacc; k2 += 16u) {
          a0 |= mask[(size_t)(wi * 64u + saccb[k2]) * (TOPM / 64) + wj];
          a1 |= mask[(size_t)(wi * 64u + saccb[k2 + 8u]) * (TOPM / 64) + wj];
        }
        for (; k2 < nacc; k2 += 8u)
          a0 |= mask[(size_t)(wi * 64u + saccb[k2]) * (TOPM / 64) + wj];
        unsigned long long accum = a0 | a1;
        if (accum) atomicOr(&removed[wj], accum);
      }
    }
    __syncthreads();
    if (sna >= MAXOUT) break;
  }
  if (t == 0) ctrs[1] = sna;
}

// ---------- grid-parallel filter ----------
__global__ __launch_bounds__(256) void k_filter(const unsigned long long* __restrict__ keys,
                                                const float4* __restrict__ boxes,
                                                const unsigned int* __restrict__ ctrs,
                                                const float4* __restrict__ abox,
                                                unsigned char* __restrict__ flags) {
  __shared__ float4 at[256];
  const int t = threadIdx.x;
  const unsigned cnt = ctrs[0], naA = ctrs[1];
  if (naA >= MAXOUT) return;
  const unsigned q = TOPM + blockIdx.x * 256 + t;
  float4 bq = make_float4(3e9f, 3e9f, 3e9f, 3e9f);
  unsigned flag = 0u;
  if (q < cnt) {
    unsigned a = 0xFFFFFFFFu - (unsigned)(keys[q] & 0xFFFFFFFFull);
    bq = boxes[a];
    flag = 1u;
  }
  for (unsigned u0 = 0; u0 < naA; u0 += 256u) {
    unsigned m = naA - u0; if (m > 256u) m = 256u;
    if ((unsigned)t < m) at[t] = abox[u0 + t];
    __syncthreads();
    if (flag) {
      for (unsigned u = 0; u < m; u++)
        if (iou_gt07(at[u], bq)) { flag = 0u; break; }
    }
    __syncthreads();
  }
  if (q < cnt) flags[q - TOPM] = (unsigned char)flag;
}

// ---------- stable compaction of surviving suffix candidates ----------
__global__ __launch_bounds__(1024) void k_compact(const unsigned long long* __restrict__ keys,
                                                  unsigned int* __restrict__ ctrs,
                                                  const unsigned char* __restrict__ flags,
                                                  unsigned int* __restrict__ said) {
  __shared__ unsigned wsum[16], wpre[16];
  __shared__ unsigned base, tot;
  const int t = threadIdx.x, wid = t >> 6, lane = t & 63;
  const unsigned cnt = ctrs[0], naA = ctrs[1];
  if (naA >= MAXOUT || cnt <= TOPM) { if (t == 0) ctrs[2] = 0u; return; }
  const unsigned n = cnt - TOPM;
  if (t == 0) base = 0u;
  __syncthreads();
  for (unsigned s = 0; s < n; s += 1024u) {
    unsigned q = s + t;
    bool pred = (q < n) && flags[q];
    unsigned long long ball = __ballot(pred);
    if (lane == 0) wsum[wid] = (unsigned)__popcll(ball);
    __syncthreads();
    if (t == 0) {
      unsigned a2 = 0;
      for (int i = 0; i < 16; i++) { wpre[i] = a2; a2 += wsum[i]; }
      tot = a2;
    }
    __syncthreads();
    if (pred) {
      unsigned pos = base + wpre[wid] +
                     (unsigned)__popcll(ball & ((lane == 0) ? 0ull : ((1ull << lane) - 1ull)));
      said[pos] = 0xFFFFFFFFu - (unsigned)(keys[TOPM + q] & 0xFFFFFFFFull);
    }
    __syncthreads();
    if (t == 0) base += tot;
    __syncthreads();
  }
  if (t == 0) ctrs[2] = base;
}

// ---------- phase B: resume chunked greedy over survivors ----------
__global__ __launch_bounds__(256) void k_nmsB(const unsigned int* __restrict__ said,
                                              const float4* __restrict__ boxes,
                                              unsigned int* __restrict__ ctrs,
                                              unsigned int* __restrict__ acc) {
  __shared__ float4 ab[MAXOUT];
  __shared__ float4 cb[64];
  __shared__ unsigned int cba[64];
  __shared__ unsigned long long selfm[64];
  __shared__ unsigned long long ssup;
  __shared__ unsigned int sna;
  const int t = threadIdx.x;
  const unsigned naA = ctrs[1], scnt = ctrs[2];
  if (naA >= MAXOUT || scnt == 0u) return;
  if (t == 0) sna = 0u;
  __syncthreads();
  for (unsigned q0 = 0; q0 < scnt; q0 += 64) {
    unsigned nr = scnt - q0; if (nr > 64u) nr = 64u;
    if (t < 64) {
      if ((unsigned)t < nr) {
        unsigned a = said[q0 + t];
        cba[t] = a;
        cb[t] = boxes[a];
      } else {
        cb[t] = make_float4(3e9f, 3e9f, 3e9f, 3e9f);
        cba[t] = 0u;
      }
    }
    if (t == 0) ssup = 0ull;
    __syncthreads();
    if (t < 64) {
      float4 bi = cb[t];
      unsigned long long bits = 0ull;
      for (int b = 0; b < 64; b++)
        if (iou_gt07(bi, cb[b])) bits |= (1ull << b);
      selfm[t] = bits;
    }
    const unsigned na0 = sna;
    unsigned long long mybits = 0ull;
    const int colg = (t & 3) * 16;
    for (unsigned u = (unsigned)(t >> 2); u < na0; u += 64u) {
      float4 au = ab[u];
#pragma unroll
      for (int b2 = 0; b2 < 16; b2++)
        if (iou_gt07(au, cb[colg + b2])) mybits |= (1ull << (colg + b2));
    }
    if (mybits) atomicOr(&ssup, mybits);
    __syncthreads();
    if (t == 0) {
      unsigned long long w = ~ssup;
      if (nr < 64u) w &= ((1ull << nr) - 1ull);
      unsigned na = sna;
      while (w && (naA + na) < MAXOUT) {
        int b = __builtin_ctzll(w);
        ab[na] = cb[b];
        acc[naA + na] = cba[b];
        na++;
        w &= ~selfm[b];
      }
      sna = na;
    }
    __syncthreads();
    if (naA + sna >= MAXOUT) break;
  }
  if (t == 0) ctrs[1] = naA + sna;
}

// ---------- write outputs (f32) ----------
__global__ void k_output(const float4* __restrict__ boxes, const float* __restrict__ score,
                         const unsigned int* __restrict__ acc, const unsigned int* __restrict__ ctrs,
                         float* __restrict__ out) {
  int tdx = blockIdx.x * 256 + threadIdx.x;
  if (tdx >= MAXOUT) return;
  unsigned na = ctrs[1];
  float4 b = make_float4(0.f, 0.f, 0.f, 0.f);
  float o0 = 0.f, o1 = 0.f;
  if (tdx < (int)na) {
    unsigned a = acc[tdx];
    b = boxes[a];
    o0 = score[2 * (size_t)a];
    o1 = score[2 * (size_t)a + 1];
  }
  out[tdx * 4 + 0] = b.x;
  out[tdx * 4 + 1] = b.y;
  out[tdx * 4 + 2] = b.z;
  out[tdx * 4 + 3] = b.w;
  out[8000 + tdx * 2 + 0] = o0;
  out[8000 + tdx * 2 + 1] = o1;
}

extern "C" void kernel_launch(void* const* d_in, const int* in_sizes, int n_in,
                              void* d_out, int out_size, void* d_ws, size_t ws_size,
                              hipStream_t stream) {
  const float* x       = (const float*)d_in[0];
  const float* conv_w  = (const float*)d_in[1];
  const float* conv_b  = (const float*)d_in[2];
  const float* bbox_w  = (const float*)d_in[3];
  const float* bbox_b  = (const float*)d_in[4];
  const float* score_w = (const float*)d_in[5];
  const float* score_b = (const float*)d_in[6];

  char* ws = (char*)d_ws;
  size_t off = 0;
  auto alloc = [&](size_t bytes) {
    void* p = ws + off;
    off = (off + bytes + 255) & ~(size_t)255;
    return p;
  };
  float* h = (float*)alloc((size_t)256 * SGRID * 4);          // 9.44 MB, alive whole run
  char*  R = (char*)alloc((size_t)13292544 + 512);            // union region
  // early views (dead after k_conv3)
  float* xpad = (float*)R;                                    // 256*98*104*4 = 10,446,848
  float* wre  = (float*)(R + 10446848);                       // 2,359,296 (ends 12,806,144)
  // late views (born after k_conv3)
  float* bbox              = (float*)(R + 0);                 // 1,327,104
  float* score             = (float*)(R + 1327104);           //   663,552
  float4* boxes            = (float4*)(R + 1990656);          // 1,327,104
  float4* sbox             = (float4*)(R + 4366336);          //   131,072
  unsigned int* sidx       = (unsigned int*)(R + 4497408);    //    32,768
  unsigned long long* mask = (unsigned long long*)(R + 4530176); // 8,388,608
  unsigned char* flags     = (unsigned char*)(R + 12918784);  //    74,752
  unsigned int* said       = (unsigned int*)(R + 12993536);   //   299,008 (ends 13,292,544)
  // DEDICATED (non-aliased) buffers — keys zeroing is safe pre-conv3:
  unsigned long long* keys = (unsigned long long*)alloc((size_t)NSORT * 8); // 1.05 MB
  unsigned int* acc        = (unsigned int*)alloc((size_t)2048 * 4);
  float4* abox             = (float4*)alloc((size_t)2048 * 16);
  unsigned int* ctrs       = (unsigned int*)alloc(64);
  unsigned int* cnt = ctrs + 0;
  (void)in_sizes; (void)n_in; (void)out_size; (void)ws_size;

  k_pad<<<2048, 256, 0, stream>>>(x, xpad, keys, ctrs);   // pad + zero keys/ctrs (no aliasing)
  k_wre<<<1024, 256, 0, stream>>>(conv_w, wre);
  k_conv3<<<dim3(96, 256 / OCB), 256, 0, stream>>>(xpad, wre, conv_b, h);

  k_conv1x1<<<dim3(36, 3), 256, 0, stream>>>(h, bbox_w, bbox_b, score_w, score_b, bbox, score);
  k_decode<<<NANCH / 256, 256, 0, stream>>>(bbox, score, boxes, keys, cnt);

  k_sort_local<<<NSORT / 4096, 1024, 0, stream>>>(keys, cnt);
  for (int k = 8192; k <= NSORT; k <<= 1) {
    for (int j = k >> 1; j >= 4096; j >>= 1)
      k_sort_global<<<NSORT / 512, 256, 0, stream>>>(keys, k, j, cnt);
    k_sort_localmerge<<<NSORT / 4096, 1024, 0, stream>>>(keys, k, cnt);
  }

  k_gather<<<TOPM / 256, 256, 0, stream>>>(keys, boxes, sbox, sidx, cnt);
  k_mask<<<dim3(TOPM / 64, TOPM / 512), 256, 0, stream>>>(sbox, mask);
  k_sweepA<<<1, 1024, 0, stream>>>(sidx, sbox, mask, ctrs, acc, abox);

  k_filter<<<(NANCH - TOPM + 255) / 256, 256, 0, stream>>>(keys, boxes, ctrs, abox, flags);
  k_compact<<<1, 1024, 0, stream>>>(keys, ctrs, flags, said);
  k_nmsB<<<1, 256, 0, stream>>>(said, boxes, ctrs, acc);

  k_output<<<(MAXOUT + 255) / 256, 256, 0, stream>>>(boxes, score, acc, ctrs, (float*)d_out);
}

// Round 23
// 767.366 us; speedup vs baseline: 1.1045x; 1.0034x over previous
//
#include <hip/hip_runtime.h>
#include <hip/hip_bf16.h>
#include <math.h>

#define SGRID 9216      // 96*96
#define NANCH 82944     // 9216*9
#define NSORT 131072    // pow2 >= worst-case candidate count (82944)
#define TOPM  8192      // phase-A window (sorted prefix)
#define MAXOUT 2000
#define OCB 16
#define XPS 104         // xpad row stride (float4-aligned)
#define XCS (98 * XPS)  // xpad channel stride = 10192

// ---------- helpers ----------
__device__ __forceinline__ bool iou_gt07(const float4 bi, const float4 bj) {
  float a1 = __fmul_rn(bi.z - bi.x, bi.w - bi.y);
  float a2 = __fmul_rn(bj.z - bj.x, bj.w - bj.y);
  float xx1 = fmaxf(bi.x, bj.x), yy1 = fmaxf(bi.y, bj.y);
  float xx2 = fminf(bi.z, bj.z), yy2 = fminf(bi.w, bj.w);
  float inter = __fmul_rn(fmaxf(xx2 - xx1, 0.f), fmaxf(yy2 - yy1, 0.f));
  float den = ((a1 + a2) - inter) + 1e-9f;
  return __fdiv_rn(inter, den) > 0.7f;
}

// ---------- fused prep: pad x + reorder w + zero keys/ctrs (ALL ranges disjoint) ----------
// xpad: R+0..10.4MB; wre: R+10.4..12.8MB; keys/ctrs: dedicated allocations.
__global__ void k_pad(const float* __restrict__ x, const float* __restrict__ w,
                      float* __restrict__ xpad, float* __restrict__ wre,
                      unsigned long long* __restrict__ keys, unsigned int* __restrict__ ctrs) {
  const size_t T1 = (size_t)256 * XCS;                 // xpad floats
  const size_t T2 = T1 + (size_t)32 * 256 * 72;        // + wre floats
  const size_t T3 = T2 + (size_t)NSORT;                // + keys words
  for (size_t i = (size_t)blockIdx.x * 256 + threadIdx.x; i < T3;
       i += (size_t)gridDim.x * 256) {
    if (i < T1) {
      int ic = (int)(i / XCS);
      int rem = (int)(i % XCS);
      int yy = rem / XPS, xx = rem % XPS;
      float v = 0.f;
      if (yy >= 1 && yy <= 96 && xx >= 1 && xx <= 96)
        v = x[(size_t)ic * SGRID + (yy - 1) * 96 + (xx - 1)];
      xpad[i] = v;
    } else if (i < T2) {
      size_t ii = i - T1;
      int c = (int)(ii / (256 * 72));
      int rem = (int)(ii % (256 * 72));
      int oc = rem / 72, j = rem % 72;
      wre[ii] = w[(size_t)oc * 2304 + c * 72 + j];
    } else {
      keys[i - T2] = 0ull;
    }
  }
  if (blockIdx.x == 0 && threadIdx.x < 8) ctrs[threadIdx.x] = 0u;
}

// ---------- conv 3x3 (256->256, SAME, relu): reg-dbuf, 1 barrier/chunk, OCB=16 ----------
// grid (96 rows, 16 oc-groups of 16), block 256: og = t>>4 (1 oc each), xg = t&15 (6 x each)
__global__ __launch_bounds__(256) void k_conv3(const float* __restrict__ xpad,
                                               const float* __restrict__ wre,
                                               const float* __restrict__ bias,
                                               float* __restrict__ h) {
  __shared__ float xsB[2][8][320];   // 8 ic x (3 rows x 104)
  __shared__ float wB[2][1152];      // 16 oc x 72
  const int y = blockIdx.x;
  const int oc0 = blockIdx.y * OCB;
  const int t = threadIdx.x;
  const int og = t >> 4;             // 16 groups of 1 oc
  const int xg = t & 15;             // 16 groups of 6 x
  float acc[6];
#pragma unroll
  for (int c = 0; c < 6; c++) acc[c] = 0.f;

  int xg_ofs[3], xl_ofs[3];
  bool xon[3];
#pragma unroll
  for (int k = 0; k < 3; k++) {
    int idx = t + k * 256;
    xon[k] = (idx < 624);
    int rowidx = idx / 26, col = idx - rowidx * 26;
    int ic = rowidx / 3, r = rowidx - ic * 3;
    if (!xon[k]) { ic = 0; r = 0; col = 0; }
    xg_ofs[k] = ic * XCS + (y + r) * XPS + col * 4;
    xl_ofs[k] = ic * 320 + r * XPS + col * 4;
  }
  bool won[2];
#pragma unroll
  for (int k = 0; k < 2; k++) won[k] = ((t + k * 256) < 288);

  float4 xv[3], wv[2];
  auto ldreg = [&](int c) {
    const float* xb = xpad + (size_t)c * 8 * XCS;
    const float* wb = wre + ((size_t)c * 256 + oc0) * 72;
#pragma unroll
    for (int k = 0; k < 3; k++)
      if (xon[k]) xv[k] = *(const float4*)(xb + xg_ofs[k]);
#pragma unroll
    for (int k = 0; k < 2; k++)
      if (won[k]) wv[k] = *(const float4*)(wb + (t + k * 256) * 4);
  };
  auto stlds = [&](int buf) {
    float* xd = &xsB[buf][0][0];
#pragma unroll
    for (int k = 0; k < 3; k++)
      if (xon[k]) *(float4*)(xd + xl_ofs[k]) = xv[k];
#pragma unroll
    for (int k = 0; k < 2; k++)
      if (won[k]) *(float4*)(&wB[buf][(t + k * 256) * 4]) = wv[k];
  };

  ldreg(0);
  stlds(0);
  ldreg(1);
  __syncthreads();
  int buf = 0;
  for (int c = 0; c < 32; c++) {
    if (c < 31) {
      stlds(buf ^ 1);
      if (c < 30) ldreg(c + 2);
    }
#pragma unroll
    for (int ic = 0; ic < 8; ic++) {
#pragma unroll
      for (int r = 0; r < 3; r++) {
        float xr[8];
#pragma unroll
        for (int u = 0; u < 8; u++) xr[u] = xsB[buf][ic][r * XPS + xg * 6 + u];
        float w0 = wB[buf][og * 72 + ic * 9 + r * 3 + 0];
        float w1 = wB[buf][og * 72 + ic * 9 + r * 3 + 1];
        float w2 = wB[buf][og * 72 + ic * 9 + r * 3 + 2];
#pragma unroll
        for (int c2 = 0; c2 < 6; c2++)
          acc[c2] += xr[c2] * w0 + xr[c2 + 1] * w1 + xr[c2 + 2] * w2;
      }
    }
    __syncthreads();
    buf ^= 1;
  }
  {
    int oc = oc0 + og;
    float bb = bias[oc];
#pragma unroll
    for (int c = 0; c < 6; c++) {
      float v = acc[c] + bb;
      h[(size_t)oc * SGRID + y * 96 + xg * 6 + c] = v > 0.f ? v : 0.f;
    }
  }
}

// ---------- 1x1 heads: channel-split, grid (36 pos-groups, 3 ch-groups of 18) ----------
__global__ __launch_bounds__(256) void k_conv1x1(const float* __restrict__ h,
                                                 const float* __restrict__ bw, const float* __restrict__ bb,
                                                 const float* __restrict__ sw, const float* __restrict__ sb,
                                                 float* __restrict__ bbox, float* __restrict__ score) {
  __shared__ float wcat[18][256];
  const int t = threadIdx.x;
  const int cg = blockIdx.y;
  for (int idx = t; idx < 18 * 64; idx += 256) {
    int cl = idx >> 6, k4 = idx & 63;
    int c = cg * 18 + cl;
    const float* src = (c < 36) ? (bw + c * 256) : (sw + (c - 36) * 256);
    float4 v = *(const float4*)(src + k4 * 4);
    *(float4*)(&wcat[cl][k4 * 4]) = v;
  }
  __syncthreads();
  const int p = blockIdx.x * 256 + t;
  float accA[18];
#pragma unroll
  for (int cl = 0; cl < 18; cl++) accA[cl] = 0.f;
  for (int k0 = 0; k0 < 256; k0 += 8) {
    float ha[8];
#pragma unroll
    for (int u = 0; u < 8; u++) ha[u] = h[(size_t)(k0 + u) * SGRID + p];
#pragma unroll
    for (int cl = 0; cl < 18; cl++) {
      float4 w0 = *(const float4*)(&wcat[cl][k0]);
      float4 w1 = *(const float4*)(&wcat[cl][k0 + 4]);
      accA[cl] += ha[0] * w0.x + ha[1] * w0.y + ha[2] * w0.z + ha[3] * w0.w
                + ha[4] * w1.x + ha[5] * w1.y + ha[6] * w1.z + ha[7] * w1.w;
    }
  }
#pragma unroll
  for (int cl = 0; cl < 18; cl++) {
    int c = cg * 18 + cl;
    if (c < 36) {
      float va = accA[cl] + bb[c];
      bbox[(size_t)c * SGRID + p] = va > 0.f ? va : 0.f;
    } else {
      float va = accA[cl] + sb[c - 36];
      score[(size_t)(c - 36) * SGRID + p] = va > 0.f ? va : 0.f;
    }
  }
}

// ---------- decode + filter + candidate compaction ----------
__global__ void k_decode(const float* __restrict__ bbox, const float* __restrict__ score,
                         float4* __restrict__ boxes, unsigned long long* __restrict__ keys,
                         unsigned int* __restrict__ cnt) {
  int a = blockIdx.x * 256 + threadIdx.x;
  if (a >= NANCH) return;
  int i = a / 864;
  int rem = a - i * 864;
  int j = rem / 9;
  int k = rem - j * 9;
  const double areas[3] = {16384.0, 65536.0, 262144.0};
  int ai = k / 3, ri = k - ai * 3;
  double wr = (ri == 1) ? 2.0 : 1.0;
  double hr = (ri == 2) ? 2.0 : 1.0;
  double u = sqrt(areas[ai] / (wr * hr));
  double wd = wr * u, hd = hr * u;
  double cxd = (i + 0.5) * 16.0, cyd = (j + 0.5) * 16.0;
  float ax1 = (float)(cxd - wd * 0.5), ax2 = (float)(cxd + wd * 0.5);
  float ay1 = (float)(cyd - hd * 0.5), ay2 = (float)(cyd + hd * 0.5);
  float wa = ax2 - ax1, haa = ay2 - ay1;
  float cxa = (ax1 + ax2) * 0.5f, cya = (ay1 + ay2) * 0.5f;

  float4 br = ((const float4*)bbox)[a];
  float o0 = score[2 * (size_t)a];

  float cx = __fmul_rn(br.x, wa) + cxa;
  float cy = __fmul_rn(br.y, haa) + cya;
  float ww = __fmul_rn(expf(br.z), wa);
  float hh = __fmul_rn(expf(br.w), haa);
  float x1 = fminf(fmaxf(cx - __fmul_rn(ww, 0.5f), 0.f), 1536.f);
  float y1 = fminf(fmaxf(cy - __fmul_rn(hh, 0.5f), 0.f), 1536.f);
  float x2 = fminf(fmaxf(cx + __fmul_rn(ww, 0.5f), 0.f), 1536.f);
  float y2 = fminf(fmaxf(cy + __fmul_rn(hh, 0.5f), 0.f), 1536.f);
  boxes[a] = make_float4(x1, y1, x2, y2);
  float area = fabsf(__fmul_rn(x1 - x2, y1 - y2));
  if (o0 > 0.2f && area > 100.0f) {
    unsigned p = atomicAdd(cnt, 1u);
    keys[p] = ((unsigned long long)__float_as_uint(o0) << 32) |
              (unsigned long long)(0xFFFFFFFFu - (unsigned)a);
  }
}

// ---------- bitonic sort (descending), cnt-aware stage skipping ----------
__global__ __launch_bounds__(1024) void k_sort_local(unsigned long long* keys,
                                                     const unsigned int* __restrict__ cntp) {
  __shared__ unsigned long long s[4096];
  const int base = blockIdx.x * 4096, t = threadIdx.x;
  if ((unsigned)base >= *cntp) return;
  for (int u = t; u < 4096; u += 1024) s[u] = keys[base + u];
  __syncthreads();
  for (int k = 2; k <= 4096; k <<= 1) {
    for (int j = k >> 1; j >= 1; j >>= 1) {
      for (int m = t; m < 2048; m += 1024) {
        int i = ((m & ~(j - 1)) << 1) | (m & (j - 1));
        int l = i | j;
        bool dir = (((base + i) & k) == 0);
        unsigned long long A = s[i], B = s[l];
        bool sw = dir ? (A < B) : (A > B);
        if (sw) { s[i] = B; s[l] = A; }
      }
      __syncthreads();
    }
  }
  for (int u = t; u < 4096; u += 1024) keys[base + u] = s[u];
}

__global__ void k_sort_global(unsigned long long* keys, int k, int j,
                              const unsigned int* __restrict__ cntp) {
  if (*cntp <= (unsigned)(k >> 1)) return;
  int m = blockIdx.x * 256 + threadIdx.x;
  int i = ((m & ~(j - 1)) << 1) | (m & (j - 1));
  int l = i | j;
  bool dir = ((i & k) == 0);
  unsigned long long A = keys[i], B = keys[l];
  bool sw = dir ? (A < B) : (A > B);
  if (sw) { keys[i] = B; keys[l] = A; }
}

__global__ __launch_bounds__(1024) void k_sort_localmerge(unsigned long long* keys, int k,
                                                          const unsigned int* __restrict__ cntp) {
  if (*cntp <= (unsigned)(k >> 1)) return;
  __shared__ unsigned long long s[4096];
  const int base = blockIdx.x * 4096, t = threadIdx.x;
  for (int u = t; u < 4096; u += 1024) s[u] = keys[base + u];
  __syncthreads();
  const bool dir = ((base & k) == 0);
  for (int j = 2048; j >= 1; j >>= 1) {
    for (int m = t; m < 2048; m += 1024) {
      int i = ((m & ~(j - 1)) << 1) | (m & (j - 1));
      int l = i | j;
      unsigned long long A = s[i], B = s[l];
      bool sw = dir ? (A < B) : (A > B);
      if (sw) { s[i] = B; s[l] = A; }
    }
    __syncthreads();
  }
  for (int u = t; u < 4096; u += 1024) keys[base + u] = s[u];
}

// ---------- gather sorted top-TOPM boxes ----------
__global__ void k_gather(const unsigned long long* __restrict__ keys,
                         const float4* __restrict__ boxes,
                         float4* __restrict__ sbox, unsigned int* __restrict__ sidx,
                         const unsigned int* __restrict__ cntp) {
  int p = blockIdx.x * 256 + threadIdx.x;
  if (p >= TOPM) return;
  unsigned c = *cntp;
  if (p < (int)c) {
    unsigned a = 0xFFFFFFFFu - (unsigned)(keys[p] & 0xFFFFFFFFull);
    sbox[p] = boxes[a];
    sidx[p] = a;
  } else {
    sbox[p] = make_float4(3e9f, 3e9f, 3e9f, 3e9f);
    sidx[p] = 0u;
  }
}

// ---------- pairwise suppression mask: TOPM x TOPM bits (upper triangle) ----------
__global__ __launch_bounds__(256) void k_mask(const float4* __restrict__ sbox,
                                              unsigned long long* __restrict__ mask) {
  if ((int)(blockIdx.y * 8 + 7) < (int)blockIdx.x) return;
  __shared__ float4 jb[512];
  const int i0 = blockIdx.x * 64;
  const int j0 = blockIdx.y * 512;
  const int t = threadIdx.x;
  for (int u = t; u < 512; u += 256) jb[u] = sbox[j0 + u];
  __syncthreads();
  const int il = t & 63, grp = t >> 6;
  const int i = i0 + il;
  const float4 bi = sbox[i];
#pragma unroll
  for (int wwi = 0; wwi < 2; wwi++) {
    int w = grp * 2 + wwi;
    unsigned long long bits = 0ull;
    for (int b = 0; b < 64; b++) {
      if (iou_gt07(bi, jb[w * 64 + b])) bits |= (1ull << b);
    }
    mask[(size_t)i * (TOPM / 64) + (j0 >> 6) + w] = bits;
  }
}

// ---------- phase A sweep: exact greedy via mask rows (wave-parallel, writes abox inline) ----------
__global__ __launch_bounds__(1024) void k_sweepA(const unsigned int* __restrict__ sidx,
                                                 const float4* __restrict__ sbox,
                                                 const unsigned long long* __restrict__ mask,
                                                 unsigned int* __restrict__ ctrs,
                                                 unsigned int* __restrict__ acc,
                                                 float4* __restrict__ abox) {
  __shared__ unsigned long long removed[TOPM / 64];
  __shared__ unsigned long long selfm[2][64];
  __shared__ unsigned int sidxw[2][64];
  __shared__ unsigned char saccb[64];
  __shared__ unsigned int snacc, sna;
  const int t = threadIdx.x;
  const unsigned cnt = ctrs[0];
  const unsigned M = cnt < TOPM ? cnt : TOPM;
  const unsigned nwords = (M + 63u) >> 6;
  if (t < TOPM / 64) removed[t] = 0ull;
  if (t == 0) { sna = 0u; snacc = 0u; }
  if (nwords > 0 && t < 64) {
    selfm[0][t] = mask[(size_t)t * (TOPM / 64) + 0];
    sidxw[0][t] = sidx[t];
  }
  __syncthreads();
  for (unsigned wi = 0; wi < nwords; wi++) {
    const int cur = (int)(wi & 1u);
    if (t < 64) {
      unsigned long long myrow = selfm[cur][t];
      unsigned myidx = sidxw[cur][t];
      unsigned rem0 = M - wi * 64u;
      unsigned long long valid = (rem0 >= 64u) ? ~0ull : ((1ull << rem0) - 1ull);
      unsigned long long w = ~removed[wi] & valid;
      const unsigned na0 = sna;
      unsigned long long accbits = 0ull;
      unsigned n = 0u;
      while (w && (na0 + n) < MAXOUT) {
        int b = __builtin_ctzll(w);
        accbits |= (1ull << b);
        n++;
        unsigned long long row = __shfl(myrow, b);
        w &= ~row;
        w &= ~(1ull << b);
      }
      if ((accbits >> t) & 1ull) {
        unsigned rank = (unsigned)__popcll(accbits & ((t == 0) ? 0ull : ((1ull << t) - 1ull)));
        saccb[rank] = (unsigned char)t;
        acc[na0 + rank] = myidx;
        abox[na0 + rank] = sbox[wi * 64u + (unsigned)t];
      }
      if (t == 0) { snacc = n; sna = na0 + n; }
    }
    __syncthreads();
    if (wi + 1u < nwords && t < 64) {
      selfm[cur ^ 1][t] = mask[(size_t)((wi + 1u) * 64u + t) * (TOPM / 64) + (wi + 1u)];
      sidxw[cur ^ 1][t] = sidx[(wi + 1u) * 64u + t];
    }
    {
      const unsigned nacc = snacc;
      const int wj = t & 127, g = t >> 7;
      if (nacc && (unsigned)g < nacc && wj > (int)wi) {
        unsigned long long a0 = 0ull, a1 = 0ull;
        unsigned k2 = (unsigned)g;
        for (; k2 + 8u < nacc; k2 += 16u) {
          a0 |= mask[(size_t)(wi * 64u + saccb[k2]) * (TOPM / 64) + wj];
          a1 |= mask[(size_t)(wi * 64u + saccb[k2 + 8u]) * (TOPM / 64) + wj];
        }
        for (; k2 < nacc; k2 += 8u)
          a0 |= mask[(size_t)(wi * 64u + saccb[k2]) * (TOPM / 64) + wj];
        unsigned long long accum = a0 | a1;
        if (accum) atomicOr(&removed[wj], accum);
      }
    }
    __syncthreads();
    if (sna >= MAXOUT) break;
  }
  if (t == 0) ctrs[1] = sna;
}

// ---------- grid-parallel filter ----------
__global__ __launch_bounds__(256) void k_filter(const unsigned long long* __restrict__ keys,
                                                const float4* __restrict__ boxes,
                                                const unsigned int* __restrict__ ctrs,
                                                const float4* __restrict__ abox,
                                                unsigned char* __restrict__ flags) {
  __shared__ float4 at[256];
  const int t = threadIdx.x;
  const unsigned cnt = ctrs[0], naA = ctrs[1];
  if (naA >= MAXOUT) return;
  const unsigned q = TOPM + blockIdx.x * 256 + t;
  float4 bq = make_float4(3e9f, 3e9f, 3e9f, 3e9f);
  unsigned flag = 0u;
  if (q < cnt) {
    unsigned a = 0xFFFFFFFFu - (unsigned)(keys[q] & 0xFFFFFFFFull);
    bq = boxes[a];
    flag = 1u;
  }
  for (unsigned u0 = 0; u0 < naA; u0 += 256u) {
    unsigned m = naA - u0; if (m > 256u) m = 256u;
    if ((unsigned)t < m) at[t] = abox[u0 + t];
    __syncthreads();
    if (flag) {
      for (unsigned u = 0; u < m; u++)
        if (iou_gt07(at[u], bq)) { flag = 0u; break; }
    }
    __syncthreads();
  }
  if (q < cnt) flags[q - TOPM] = (unsigned char)flag;
}

// ---------- stable compaction of surviving suffix candidates ----------
__global__ __launch_bounds__(1024) void k_compact(const unsigned long long* __restrict__ keys,
                                                  unsigned int* __restrict__ ctrs,
                                                  const unsigned char* __restrict__ flags,
                                                  unsigned int* __restrict__ said) {
  __shared__ unsigned wsum[16], wpre[16];
  __shared__ unsigned base, tot;
  const int t = threadIdx.x, wid = t >> 6, lane = t & 63;
  const unsigned cnt = ctrs[0], naA = ctrs[1];
  if (naA >= MAXOUT || cnt <= TOPM) { if (t == 0) ctrs[2] = 0u; return; }
  const unsigned n = cnt - TOPM;
  if (t == 0) base = 0u;
  __syncthreads();
  for (unsigned s = 0; s < n; s += 1024u) {
    unsigned q = s + t;
    bool pred = (q < n) && flags[q];
    unsigned long long ball = __ballot(pred);
    if (lane == 0) wsum[wid] = (unsigned)__popcll(ball);
    __syncthreads();
    if (t == 0) {
      unsigned a2 = 0;
      for (int i = 0; i < 16; i++) { wpre[i] = a2; a2 += wsum[i]; }
      tot = a2;
    }
    __syncthreads();
    if (pred) {
      unsigned pos = base + wpre[wid] +
                     (unsigned)__popcll(ball & ((lane == 0) ? 0ull : ((1ull << lane) - 1ull)));
      said[pos] = 0xFFFFFFFFu - (unsigned)(keys[TOPM + q] & 0xFFFFFFFFull);
    }
    __syncthreads();
    if (t == 0) base += tot;
    __syncthreads();
  }
  if (t == 0) ctrs[2] = base;
}

// ---------- phase B: resume chunked greedy over survivors ----------
__global__ __launch_bounds__(256) void k_nmsB(const unsigned int* __restrict__ said,
                                              const float4* __restrict__ boxes,
                                              unsigned int* __restrict__ ctrs,
                                              unsigned int* __restrict__ acc) {
  __shared__ float4 ab[MAXOUT];
  __shared__ float4 cb[64];
  __shared__ unsigned int cba[64];
  __shared__ unsigned long long selfm[64];
  __shared__ unsigned long long ssup;
  __shared__ unsigned int sna;
  const int t = threadIdx.x;
  const unsigned naA = ctrs[1], scnt = ctrs[2];
  if (naA >= MAXOUT || scnt == 0u) return;
  if (t == 0) sna = 0u;
  __syncthreads();
  for (unsigned q0 = 0; q0 < scnt; q0 += 64) {
    unsigned nr = scnt - q0; if (nr > 64u) nr = 64u;
    if (t < 64) {
      if ((unsigned)t < nr) {
        unsigned a = said[q0 + t];
        cba[t] = a;
        cb[t] = boxes[a];
      } else {
        cb[t] = make_float4(3e9f, 3e9f, 3e9f, 3e9f);
        cba[t] = 0u;
      }
    }
    if (t == 0) ssup = 0ull;
    __syncthreads();
    if (t < 64) {
      float4 bi = cb[t];
      unsigned long long bits = 0ull;
      for (int b = 0; b < 64; b++)
        if (iou_gt07(bi, cb[b])) bits |= (1ull << b);
      selfm[t] = bits;
    }
    const unsigned na0 = sna;
    unsigned long long mybits = 0ull;
    const int colg = (t & 3) * 16;
    for (unsigned u = (unsigned)(t >> 2); u < na0; u += 64u) {
      float4 au = ab[u];
#pragma unroll
      for (int b2 = 0; b2 < 16; b2++)
        if (iou_gt07(au, cb[colg + b2])) mybits |= (1ull << (colg + b2));
    }
    if (mybits) atomicOr(&ssup, mybits);
    __syncthreads();
    if (t == 0) {
      unsigned long long w = ~ssup;
      if (nr < 64u) w &= ((1ull << nr) - 1ull);
      unsigned na = sna;
      while (w && (naA + na) < MAXOUT) {
        int b = __builtin_ctzll(w);
        ab[na] = cb[b];
        acc[naA + na] = cba[b];
        na++;
        w &= ~selfm[b];
      }
      sna = na;
    }
    __syncthreads();
    if (naA + sna >= MAXOUT) break;
  }
  if (t == 0) ctrs[1] = naA + sna;
}

// ---------- write outputs (f32) ----------
__global__ void k_output(const float4* __restrict__ boxes, const float* __restrict__ score,
                         const unsigned int* __restrict__ acc, const unsigned int* __restrict__ ctrs,
                         float* __restrict__ out) {
  int tdx = blockIdx.x * 256 + threadIdx.x;
  if (tdx >= MAXOUT) return;
  unsigned na = ctrs[1];
  float4 b = make_float4(0.f, 0.f, 0.f, 0.f);
  float o0 = 0.f, o1 = 0.f;
  if (tdx < (int)na) {
    unsigned a = acc[tdx];
    b = boxes[a];
    o0 = score[2 * (size_t)a];
    o1 = score[2 * (size_t)a + 1];
  }
  out[tdx * 4 + 0] = b.x;
  out[tdx * 4 + 1] = b.y;
  out[tdx * 4 + 2] = b.z;
  out[tdx * 4 + 3] = b.w;
  out[8000 + tdx * 2 + 0] = o0;
  out[8000 + tdx * 2 + 1] = o1;
}

extern "C" void kernel_launch(void* const* d_in, const int* in_sizes, int n_in,
                              void* d_out, int out_size, void* d_ws, size_t ws_size,
                              hipStream_t stream) {
  const float* x       = (const float*)d_in[0];
  const float* conv_w  = (const float*)d_in[1];
  const float* conv_b  = (const float*)d_in[2];
  const float* bbox_w  = (const float*)d_in[3];
  const float* bbox_b  = (const float*)d_in[4];
  const float* score_w = (const float*)d_in[5];
  const float* score_b = (const float*)d_in[6];

  char* ws = (char*)d_ws;
  size_t off = 0;
  auto alloc = [&](size_t bytes) {
    void* p = ws + off;
    off = (off + bytes + 255) & ~(size_t)255;
    return p;
  };
  float* h = (float*)alloc((size_t)256 * SGRID * 4);          // 9.44 MB, alive whole run
  char*  R = (char*)alloc((size_t)13292544 + 512);            // union region
  // early views (dead after k_conv3)
  float* xpad = (float*)R;                                    // 256*98*104*4 = 10,446,848
  float* wre  = (float*)(R + 10446848);                       // 2,359,296 (ends 12,806,144)
  // late views (born after k_conv3)
  float* bbox              = (float*)(R + 0);                 // 1,327,104
  float* score             = (float*)(R + 1327104);           //   663,552
  float4* boxes            = (float4*)(R + 1990656);          // 1,327,104
  float4* sbox             = (float4*)(R + 4366336);          //   131,072
  unsigned int* sidx       = (unsigned int*)(R + 4497408);    //    32,768
  unsigned long long* mask = (unsigned long long*)(R + 4530176); // 8,388,608
  unsigned char* flags     = (unsigned char*)(R + 12918784);  //    74,752
  unsigned int* said       = (unsigned int*)(R + 12993536);   //   299,008 (ends 13,292,544)
  // DEDICATED (non-aliased) buffers — keys zeroing is safe pre-conv3:
  unsigned long long* keys = (unsigned long long*)alloc((size_t)NSORT * 8); // 1.05 MB
  unsigned int* acc        = (unsigned int*)alloc((size_t)2048 * 4);
  float4* abox             = (float4*)alloc((size_t)2048 * 16);
  unsigned int* ctrs       = (unsigned int*)alloc(64);
  unsigned int* cnt = ctrs + 0;
  (void)in_sizes; (void)n_in; (void)out_size; (void)ws_size;

  k_pad<<<2048, 256, 0, stream>>>(x, conv_w, xpad, wre, keys, ctrs);  // pad + wre + zero keys/ctrs
  k_conv3<<<dim3(96, 256 / OCB), 256, 0, stream>>>(xpad, wre, conv_b, h);

  k_conv1x1<<<dim3(36, 3), 256, 0, stream>>>(h, bbox_w, bbox_b, score_w, score_b, bbox, score);
  k_decode<<<NANCH / 256, 256, 0, stream>>>(bbox, score, boxes, keys, cnt);

  k_sort_local<<<NSORT / 4096, 1024, 0, stream>>>(keys, cnt);
  for (int k = 8192; k <= NSORT; k <<= 1) {
    for (int j = k >> 1; j >= 4096; j >>= 1)
      k_sort_global<<<NSORT / 512, 256, 0, stream>>>(keys, k, j, cnt);
    k_sort_localmerge<<<NSORT / 4096, 1024, 0, stream>>>(keys, k, cnt);
  }

  k_gather<<<TOPM / 256, 256, 0, stream>>>(keys, boxes, sbox, sidx, cnt);
  k_mask<<<dim3(TOPM / 64, TOPM / 512), 256, 0, stream>>>(sbox, mask);
  k_sweepA<<<1, 1024, 0, stream>>>(sidx, sbox, mask, ctrs, acc, abox);

  k_filter<<<(NANCH - TOPM + 255) / 256, 256, 0, stream>>>(keys, boxes, ctrs, abox, flags);
  k_compact<<<1, 1024, 0, stream>>>(keys, ctrs, flags, said);
  k_nmsB<<<1, 256, 0, stream>>>(said, boxes, ctrs, acc);

  k_output<<<(MAXOUT + 255) / 256, 256, 0, stream>>>(boxes, score, acc, ctrs, (float*)d_out);
}